// Round 1
// baseline (5674.184 us; speedup 1.0000x reference)
//
#include <hip/hip_runtime.h>
#include <hip/hip_bf16.h>
#include <math.h>

#define EPSV 1e-10f
#define BNEPS 1e-5f
#define INV_SQRT2 0.70710678118654752440f

// ---------------------------------------------------------------------------
// Weight prep: e_w, and (lrconv: var_w | ver2: e_w^2)
// ---------------------------------------------------------------------------
__global__ void prep_w(const float* __restrict__ a, const float* __restrict__ b,
                       float* __restrict__ WA, float* __restrict__ WB,
                       int n, int ver2) {
    for (int i = blockIdx.x * blockDim.x + threadIdx.x; i < n; i += gridDim.x * blockDim.x) {
        float p0 = 1.f / (1.f + expf(-a[i]));
        float sb = 1.f / (1.f + expf(-b[i]));
        float p1 = (1.f - p0) * sb;
        float ew = 2.f * p1 - (1.f - p0);
        float ew2 = 1.f - p0;
        WA[i] = ew;
        WB[i] = ver2 ? (ew * ew) : (ew2 - ew * ew);
    }
}

// s[co][ky][kx] = sum_ci e_w2 = sum_ci sigmoid(-alpha)
__global__ void prep_s(const float* __restrict__ alpha, float* __restrict__ s, int Ci) {
    int co = blockIdx.x;
    int lane = threadIdx.x; // 64 threads
    float acc[9];
#pragma unroll
    for (int k = 0; k < 9; k++) acc[k] = 0.f;
    for (int ci = lane; ci < Ci; ci += 64) {
        const float* p = alpha + ((long)co * Ci + ci) * 9;
#pragma unroll
        for (int k = 0; k < 9; k++) acc[k] += 1.f / (1.f + expf(p[k]));
    }
#pragma unroll
    for (int k = 0; k < 9; k++) {
        for (int off = 32; off > 0; off >>= 1) acc[k] += __shfl_down(acc[k], off);
    }
    if (lane == 0) {
#pragma unroll
        for (int k = 0; k < 9; k++) s[co * 9 + k] = acc[k];
    }
}

// ---------------------------------------------------------------------------
// Generic fused LRnet conv.
// MODE 0: lrconv      -> out = erf((convA+bias) / (sqrt(convB+eps)*sqrt2))
// MODE 1: ver2        -> m=convA+bias; v=ones-convB; out = erf(m/(sqrt(v+eps)*sqrt2))
// MODE 2: ver2 sample -> out = m + sqrt(v+eps)*epsbuf
// convA: input * WA ; convB: input^2 * WB
// ---------------------------------------------------------------------------
template<int Ci, int Hin, int Win, int Co, int Hout, int Wout, int STRIDE,
         int BPB, int NSP, int COB, int MODE>
__global__ __launch_bounds__(256) void conv_k(
    const float* __restrict__ in, const float* __restrict__ WA,
    const float* __restrict__ WB, const float* __restrict__ bias,
    const float* __restrict__ ssum, const float* __restrict__ epsbuf,
    float* __restrict__ out)
{
    constexpr int TS = Hout * Wout;
    constexpr int SLOTS = BPB * TS;
    constexpr int SPT = SLOTS / NSP;
    constexpr int GCO = 256 / NSP;
    constexpr int NCO = COB / GCO;
    constexpr int PW = Win + 2;
    constexpr int PH = Hin + 2;
    constexpr int PLANE = PH * PW;
    static_assert(SPT * NSP == SLOTS, "spt");
    static_assert(GCO * NCO == COB, "nco");

    __shared__ float tile[BPB * PLANE];
    __shared__ float wa[COB * 12];
    __shared__ float wb[COB * 12];

    const int tid = threadIdx.x;
    const int nb_cog = Co / COB;
    const int b0 = (blockIdx.x / nb_cog) * BPB;
    const int co_base = (blockIdx.x % nb_cog) * COB;

    const int slot0 = tid % NSP;
    const int cog = tid / NSP;

    for (int i = tid; i < BPB * PLANE; i += 256) tile[i] = 0.f;
    __syncthreads();

    float accA[NCO][SPT];
    float accB[NCO][SPT];
#pragma unroll
    for (int c = 0; c < NCO; c++)
#pragma unroll
        for (int k = 0; k < SPT; k++) { accA[c][k] = 0.f; accB[c][k] = 0.f; }

    for (int ci = 0; ci < Ci; ++ci) {
        // stage input planes (interior; borders stay zero)
        for (int i = tid; i < BPB * Hin * Win; i += 256) {
            int bl = i / (Hin * Win);
            int r = i % (Hin * Win);
            int y = r / Win, x = r % Win;
            tile[bl * PLANE + (y + 1) * PW + (x + 1)] =
                in[(((long)(b0 + bl) * Ci + ci) * Hin + y) * Win + x];
        }
        // stage weights, padded to 12 floats per co
        for (int i = tid; i < COB * 9; i += 256) {
            int c = i / 9, k = i % 9;
            long gi = ((long)(co_base + c) * Ci + ci) * 9 + k;
            wa[c * 12 + k] = WA[gi];
            wb[c * 12 + k] = WB[gi];
        }
        __syncthreads();

        float iv[SPT][9], sq[SPT][9];
#pragma unroll
        for (int k = 0; k < SPT; k++) {
            int slot = slot0 + k * NSP;
            int bl = slot / TS;
            int sp = slot % TS;
            int y = sp / Wout, x = sp % Wout;
            const float* tp = &tile[bl * PLANE + (y * STRIDE) * PW + x * STRIDE];
#pragma unroll
            for (int j = 0; j < 9; j++) {
                float v = tp[(j / 3) * PW + (j % 3)];
                iv[k][j] = v; sq[k][j] = v * v;
            }
        }
#pragma unroll
        for (int c = 0; c < NCO; c++) {
            const int cl = cog * NCO + c;
            const float4* wap = (const float4*)&wa[cl * 12];
            const float4* wbp = (const float4*)&wb[cl * 12];
            float4 A0 = wap[0], A1 = wap[1]; float A2 = wa[cl * 12 + 8];
            float4 B0 = wbp[0], B1 = wbp[1]; float B2 = wb[cl * 12 + 8];
#pragma unroll
            for (int k = 0; k < SPT; k++) {
                float a = accA[c][k];
                a = fmaf(iv[k][0], A0.x, a); a = fmaf(iv[k][1], A0.y, a);
                a = fmaf(iv[k][2], A0.z, a); a = fmaf(iv[k][3], A0.w, a);
                a = fmaf(iv[k][4], A1.x, a); a = fmaf(iv[k][5], A1.y, a);
                a = fmaf(iv[k][6], A1.z, a); a = fmaf(iv[k][7], A1.w, a);
                a = fmaf(iv[k][8], A2, a);
                accA[c][k] = a;
                float b = accB[c][k];
                b = fmaf(sq[k][0], B0.x, b); b = fmaf(sq[k][1], B0.y, b);
                b = fmaf(sq[k][2], B0.z, b); b = fmaf(sq[k][3], B0.w, b);
                b = fmaf(sq[k][4], B1.x, b); b = fmaf(sq[k][5], B1.y, b);
                b = fmaf(sq[k][6], B1.z, b); b = fmaf(sq[k][7], B1.w, b);
                b = fmaf(sq[k][8], B2, b);
                accB[c][k] = b;
            }
        }
        __syncthreads();
    }

    // epilogue
#pragma unroll
    for (int c = 0; c < NCO; c++) {
        int co = co_base + cog * NCO + c;
        float bs = bias[co];
#pragma unroll
        for (int k = 0; k < SPT; k++) {
            int slot = slot0 + k * NSP;
            int bl = slot / TS;
            int sp = slot % TS;
            int y = sp / Wout, x = sp % Wout;
            long oidx = (((long)(b0 + bl) * Co + co) * Hout + y) * Wout + x;
            float m = accA[c][k] + bs;
            float v;
            if constexpr (MODE == 0) {
                v = accB[c][k];
            } else {
                float ones = 0.f;
#pragma unroll
                for (int ky = 0; ky < 3; ky++) {
                    int iy = y * STRIDE - 1 + ky;
                    if (iy < 0 || iy >= Hin) continue;
#pragma unroll
                    for (int kx = 0; kx < 3; kx++) {
                        int ix = x * STRIDE - 1 + kx;
                        if (ix < 0 || ix >= Win) continue;
                        ones += ssum[co * 9 + ky * 3 + kx];
                    }
                }
                v = ones - accB[c][k];
            }
            if constexpr (MODE == 2) {
                out[oidx] = m + sqrtf(v + EPSV) * epsbuf[oidx];
            } else {
                float sigma = sqrtf(v + EPSV);
                out[oidx] = erff(m / sigma * INV_SQRT2);
            }
        }
    }
}

// ---------------------------------------------------------------------------
// BatchNorm: stats (atomic) + apply(+relu, in place)
// ---------------------------------------------------------------------------
__global__ void bn_stats(const float* __restrict__ h, float* __restrict__ st,
                         int C, int HW, int Bchunk) {
    int c = blockIdx.x;
    int chunk = blockIdx.y;
    int tid = threadIdx.x;
    float s = 0.f, s2 = 0.f;
    int total = Bchunk * HW;
    int bbase = chunk * Bchunk;
    for (int j = tid; j < total; j += 256) {
        int b = bbase + j / HW;
        int i = j % HW;
        float v = h[((long)b * C + c) * HW + i];
        s += v; s2 += v * v;
    }
    for (int off = 32; off > 0; off >>= 1) {
        s += __shfl_down(s, off);
        s2 += __shfl_down(s2, off);
    }
    __shared__ float red[8];
    int wid = tid >> 6, lane = tid & 63;
    if (lane == 0) { red[wid] = s; red[4 + wid] = s2; }
    __syncthreads();
    if (tid == 0) {
        float a = red[0] + red[1] + red[2] + red[3];
        float b = red[4] + red[5] + red[6] + red[7];
        atomicAdd(&st[c], a);
        atomicAdd(&st[C + c], b);
    }
}

__global__ void bn_apply(float* __restrict__ h, const float* __restrict__ st,
                         const float* __restrict__ gamma, const float* __restrict__ beta,
                         int C, int HW, long N, float invN) {
    for (long idx = (long)blockIdx.x * blockDim.x + threadIdx.x; idx < N;
         idx += (long)gridDim.x * blockDim.x) {
        int c = (int)((idx / HW) % C);
        float mean = st[c] * invN;
        float var = st[C + c] * invN - mean * mean;
        float v = gamma[c] * (h[idx] - mean) * rsqrtf(var + BNEPS) + beta[c];
        h[idx] = v > 0.f ? v : 0.f;
    }
}

// ---------------------------------------------------------------------------
// FC1: out[256,1024] = relu(A[256,8192] @ W[1024,8192]^T + b)
// block = 256 thr (16x16, each 2x2), tile 32(batch) x 32(out), K-tile 64
// ---------------------------------------------------------------------------
__global__ __launch_bounds__(256) void fc1_k(const float* __restrict__ A,
                                             const float* __restrict__ W,
                                             const float* __restrict__ bias,
                                             float* __restrict__ out) {
    __shared__ float As[32][66];
    __shared__ float Ws[32][66];
    int tid = threadIdx.x;
    int tx = tid % 16, ty = tid / 16;
    int ob = blockIdx.y * 32;  // batch base
    int oo = blockIdx.x * 32;  // out base
    float acc00 = 0.f, acc01 = 0.f, acc10 = 0.f, acc11 = 0.f;
    for (int k0 = 0; k0 < 8192; k0 += 64) {
        for (int i = tid; i < 512; i += 256) {
            int r = i / 16, q = i % 16;
            float4 av = *(const float4*)&A[(long)(ob + r) * 8192 + k0 + q * 4];
            As[r][q * 4 + 0] = av.x; As[r][q * 4 + 1] = av.y;
            As[r][q * 4 + 2] = av.z; As[r][q * 4 + 3] = av.w;
            float4 wv = *(const float4*)&W[(long)(oo + r) * 8192 + k0 + q * 4];
            Ws[r][q * 4 + 0] = wv.x; Ws[r][q * 4 + 1] = wv.y;
            Ws[r][q * 4 + 2] = wv.z; Ws[r][q * 4 + 3] = wv.w;
        }
        __syncthreads();
#pragma unroll
        for (int kk = 0; kk < 64; kk++) {
            float a0 = As[ty * 2][kk], a1 = As[ty * 2 + 1][kk];
            float w0 = Ws[tx * 2][kk], w1 = Ws[tx * 2 + 1][kk];
            acc00 = fmaf(a0, w0, acc00); acc01 = fmaf(a0, w1, acc01);
            acc10 = fmaf(a1, w0, acc10); acc11 = fmaf(a1, w1, acc11);
        }
        __syncthreads();
    }
    float b0 = bias[oo + tx * 2], b1 = bias[oo + tx * 2 + 1];
    float v;
    v = acc00 + b0; out[(long)(ob + ty * 2) * 1024 + oo + tx * 2]     = v > 0.f ? v : 0.f;
    v = acc01 + b1; out[(long)(ob + ty * 2) * 1024 + oo + tx * 2 + 1] = v > 0.f ? v : 0.f;
    v = acc10 + b0; out[(long)(ob + ty * 2 + 1) * 1024 + oo + tx * 2]     = v > 0.f ? v : 0.f;
    v = acc11 + b1; out[(long)(ob + ty * 2 + 1) * 1024 + oo + tx * 2 + 1] = v > 0.f ? v : 0.f;
}

// FC2: out[256,10] = A[256,1024] @ W[10,1024]^T + b
__global__ void fc2_k(const float* __restrict__ A, const float* __restrict__ W,
                      const float* __restrict__ b2, float* __restrict__ out) {
    int bb = blockIdx.x;
    int tid = threadIdx.x;
    float acc[10];
#pragma unroll
    for (int o = 0; o < 10; o++) acc[o] = 0.f;
    const float* arow = A + (long)bb * 1024;
    for (int k = tid; k < 1024; k += 256) {
        float a = arow[k];
#pragma unroll
        for (int o = 0; o < 10; o++) acc[o] = fmaf(a, W[o * 1024 + k], acc[o]);
    }
#pragma unroll
    for (int o = 0; o < 10; o++)
        for (int off = 32; off > 0; off >>= 1) acc[o] += __shfl_down(acc[o], off);
    __shared__ float red[10][4];
    int wid = tid >> 6, lane = tid & 63;
    if (lane == 0) {
#pragma unroll
        for (int o = 0; o < 10; o++) red[o][wid] = acc[o];
    }
    __syncthreads();
    if (tid < 10)
        out[bb * 10 + tid] = red[tid][0] + red[tid][1] + red[tid][2] + red[tid][3] + b2[tid];
}

// ---------------------------------------------------------------------------
extern "C" void kernel_launch(void* const* d_in, const int* in_sizes, int n_in,
                              void* d_out, int out_size, void* d_ws, size_t ws_size,
                              hipStream_t stream) {
    const float* x     = (const float*)d_in[0];
    const float* a1 = (const float*)d_in[1];  const float* b1 = (const float*)d_in[2];  const float* c1 = (const float*)d_in[3];
    const float* a2 = (const float*)d_in[4];  const float* b2 = (const float*)d_in[5];  const float* c2 = (const float*)d_in[6];
    const float* a3 = (const float*)d_in[7];  const float* b3 = (const float*)d_in[8];  const float* c3 = (const float*)d_in[9];
    const float* a4 = (const float*)d_in[10]; const float* b4 = (const float*)d_in[11]; const float* c4 = (const float*)d_in[12];
    const float* a5 = (const float*)d_in[13]; const float* b5 = (const float*)d_in[14]; const float* c5 = (const float*)d_in[15];
    const float* a6 = (const float*)d_in[16]; const float* b6 = (const float*)d_in[17]; const float* c6 = (const float*)d_in[18];
    const float* g3  = (const float*)d_in[19]; const float* be3 = (const float*)d_in[20];
    const float* g6  = (const float*)d_in[21]; const float* be6 = (const float*)d_in[22];
    const float* fc1w = (const float*)d_in[23]; const float* fc1b = (const float*)d_in[24];
    const float* fc2w = (const float*)d_in[25]; const float* fc2b = (const float*)d_in[26];
    const float* eps3 = (const float*)d_in[27]; const float* eps6 = (const float*)d_in[28];

    const int n1 = 128 * 3 * 9, n2 = 128 * 128 * 9, n3 = 256 * 128 * 9;
    const int n4 = 256 * 256 * 9, n5 = 512 * 256 * 9, n6 = 512 * 512 * 9;

    float* w = (float*)d_ws;
    size_t off = 0;
    auto alloc = [&](size_t n) { float* p = w + off; off += n; return p; };
    float* wa1 = alloc(n1); float* wb1 = alloc(n1);
    float* wa2 = alloc(n2); float* wb2 = alloc(n2);
    float* wa3 = alloc(n3); float* wb3 = alloc(n3);
    float* wa4 = alloc(n4); float* wb4 = alloc(n4);
    float* wa5 = alloc(n5); float* wb5 = alloc(n5);
    float* wa6 = alloc(n6); float* wb6 = alloc(n6);
    float* s2 = alloc(128 * 9);
    float* s3 = alloc(256 * 9);
    float* s5 = alloc(512 * 9);
    float* s6 = alloc(512 * 9);
    float* st3 = alloc(512);
    float* st6 = alloc(1024);
    float* R1 = alloc(33554432);  // ex1 / h3 / ex5 / fc1out
    float* R2 = alloc(8388608);   // ex2 / ex4 / h6
    (void)ws_size; (void)n_in; (void)in_sizes; (void)out_size;

    float* ex1 = R1;
    float* ex2 = R2;
    float* h3  = R1;
    float* ex4 = R2;
    float* ex5 = R1;
    float* h6  = R2;
    float* fco = R1;

    // weight prep
    prep_w<<<(n1 + 255) / 256, 256, 0, stream>>>(a1, b1, wa1, wb1, n1, 0);
    prep_w<<<(n2 + 255) / 256, 256, 0, stream>>>(a2, b2, wa2, wb2, n2, 1);
    prep_w<<<(n3 + 255) / 256, 256, 0, stream>>>(a3, b3, wa3, wb3, n3, 1);
    prep_w<<<(n4 + 255) / 256, 256, 0, stream>>>(a4, b4, wa4, wb4, n4, 0);
    prep_w<<<(n5 + 255) / 256, 256, 0, stream>>>(a5, b5, wa5, wb5, n5, 1);
    prep_w<<<(n6 + 255) / 256, 256, 0, stream>>>(a6, b6, wa6, wb6, n6, 1);
    prep_s<<<128, 64, 0, stream>>>(a2, s2, 128);
    prep_s<<<256, 64, 0, stream>>>(a3, s3, 128);
    prep_s<<<512, 64, 0, stream>>>(a5, s5, 256);
    prep_s<<<512, 64, 0, stream>>>(a6, s6, 512);

    // L1: [256,3,32,32] -> ex1 [256,128,32,32]
    conv_k<3, 32, 32, 128, 32, 32, 1, 1, 256, 8, 0>
        <<<256 * 16, 256, 0, stream>>>(x, wa1, wb1, c1, nullptr, nullptr, ex1);
    // L2: ex1 -> ex2 [256,128,16,16], stride 2
    conv_k<128, 32, 32, 128, 16, 16, 2, 1, 64, 32, 1>
        <<<256 * 4, 256, 0, stream>>>(ex1, wa2, wb2, c2, s2, nullptr, ex2);
    // L3: ex2 -> h3 [256,256,16,16] (sample with eps3)
    conv_k<128, 16, 16, 256, 16, 16, 1, 1, 64, 32, 2>
        <<<256 * 8, 256, 0, stream>>>(ex2, wa3, wb3, c3, s3, eps3, h3);
    // BN3 + relu (in place on h3)
    hipMemsetAsync(st3, 0, 512 * sizeof(float), stream);
    bn_stats<<<dim3(256, 8), 256, 0, stream>>>(h3, st3, 256, 256, 32);
    bn_apply<<<8192, 256, 0, stream>>>(h3, st3, g3, be3, 256, 256,
                                       (long)256 * 256 * 256, 1.f / 65536.f);
    // L4: h3 -> ex4 [256,256,8,8], stride 2
    conv_k<256, 16, 16, 256, 8, 8, 2, 2, 64, 32, 0>
        <<<128 * 8, 256, 0, stream>>>(h3, wa4, wb4, c4, nullptr, nullptr, ex4);
    // L5: ex4 -> ex5 [256,512,8,8]
    conv_k<256, 8, 8, 512, 8, 8, 1, 2, 64, 32, 1>
        <<<128 * 16, 256, 0, stream>>>(ex4, wa5, wb5, c5, s5, nullptr, ex5);
    // L6: ex5 -> h6 [256,512,4,4], stride 2 (sample with eps6)
    conv_k<512, 8, 8, 512, 4, 4, 2, 4, 32, 64, 2>
        <<<64 * 8, 256, 0, stream>>>(ex5, wa6, wb6, c6, s6, eps6, h6);
    // BN6 + relu (in place on h6)
    hipMemsetAsync(st6, 0, 1024 * sizeof(float), stream);
    bn_stats<<<dim3(512, 8), 256, 0, stream>>>(h6, st6, 512, 16, 32);
    bn_apply<<<2048, 256, 0, stream>>>(h6, st6, g6, be6, 512, 16,
                                       (long)256 * 512 * 16, 1.f / 4096.f);
    // FC1 + relu: h6 flat [256,8192] -> fco [256,1024]
    fc1_k<<<dim3(32, 8), 256, 0, stream>>>(h6, fc1w, fc1b, fco);
    // FC2: -> d_out [256,10]
    fc2_k<<<256, 256, 0, stream>>>(fco, fc2w, fc2b, (float*)d_out);
}

// Round 2
// 1592.688 us; speedup vs baseline: 3.5626x; 3.5626x over previous
//
#include <hip/hip_runtime.h>
#include <hip/hip_bf16.h>
#include <math.h>

#define EPSV 1e-10f
#define BNEPS 1e-5f
#define INV_SQRT2 0.70710678118654752440f

typedef __attribute__((ext_vector_type(8))) short short8;
typedef __attribute__((ext_vector_type(4))) float f32x4;

__device__ __forceinline__ float bf2f(unsigned short u) {
    union { unsigned int i; float f; } c; c.i = ((unsigned int)u) << 16; return c.f;
}
__device__ __forceinline__ unsigned short f2bf(float f) {
    unsigned int u = __float_as_uint(f);
    return (unsigned short)((u + 0x7FFFu + ((u >> 16) & 1u)) >> 16);
}

// ---------------------------------------------------------------------------
// L1 weight prep (fp32, OIHW kept): e_w and var_w
// ---------------------------------------------------------------------------
__global__ void prep_w(const float* __restrict__ a, const float* __restrict__ b,
                       float* __restrict__ WA, float* __restrict__ WB, int n) {
    for (int i = blockIdx.x * blockDim.x + threadIdx.x; i < n; i += gridDim.x * blockDim.x) {
        float p0 = 1.f / (1.f + expf(-a[i]));
        float sb = 1.f / (1.f + expf(-b[i]));
        float p1 = (1.f - p0) * sb;
        float ew = 2.f * p1 - (1.f - p0);
        float ew2 = 1.f - p0;
        WA[i] = ew;
        WB[i] = ew2 - ew * ew;
    }
}

// ---------------------------------------------------------------------------
// Pack ternary-stat weights into MFMA A-fragment order (bf16).
// index: ((((cv*9+pos)*NCH + ch)*MFg + mf)*64 + lane)*8 + j
//   co = mf*16 + (lane&15), ci = ch*32 + (lane>>4)*8 + j
// cv=0 -> e_w ; cv=1 -> (ver2 ? e_w^2 : var_w)
// ---------------------------------------------------------------------------
__global__ void prep_pack(const float* __restrict__ a, const float* __restrict__ b,
                          unsigned short* __restrict__ pk, int Ci, int Co, int ver2, int total) {
    int idx = blockIdx.x * 256 + threadIdx.x;
    if (idx >= total) return;
    int lane = idx & 63;
    int MFg = Co >> 4, NCH = Ci >> 5;
    int mfch = idx >> 6;
    int mf = mfch % MFg;
    int chpos = mfch / MFg;
    int ch = chpos % NCH;
    int pos = chpos / NCH;
    int co = mf * 16 + (lane & 15);
    int cib = ch * 32 + (lane >> 4) * 8;
    unsigned int wa[4], wb[4];
#pragma unroll
    for (int j = 0; j < 8; j++) {
        long s = ((long)co * Ci + cib + j) * 9 + pos;
        float p0 = 1.f / (1.f + expf(-a[s]));
        float sb = 1.f / (1.f + expf(-b[s]));
        float p1 = (1.f - p0) * sb;
        float ew = 2.f * p1 - (1.f - p0);
        float ew2 = 1.f - p0;
        unsigned int ha = f2bf(ew);
        unsigned int hb = f2bf(ver2 ? ew * ew : ew2 - ew * ew);
        if (j & 1) { wa[j >> 1] |= ha << 16; wb[j >> 1] |= hb << 16; }
        else       { wa[j >> 1] = ha;        wb[j >> 1] = hb; }
    }
    long b0 = (((long)(0 * 9 + pos) * NCH + ch) * MFg + mf) * 64 + lane;
    long b1 = (((long)(1 * 9 + pos) * NCH + ch) * MFg + mf) * 64 + lane;
    uint4 va; va.x = wa[0]; va.y = wa[1]; va.z = wa[2]; va.w = wa[3];
    uint4 vb; vb.x = wb[0]; vb.y = wb[1]; vb.z = wb[2]; vb.w = wb[3];
    *(uint4*)(pk + b0 * 8) = va;
    *(uint4*)(pk + b1 * 8) = vb;
}

// ssum[co][k] = sum_ci sigmoid(-alpha)   (= sum_ci E[w^2])
__global__ void prep_s(const float* __restrict__ alpha, float* __restrict__ s, int Ci) {
    int co = blockIdx.x;
    int lane = threadIdx.x; // 64
    float acc[9];
#pragma unroll
    for (int k = 0; k < 9; k++) acc[k] = 0.f;
    for (int ci = lane; ci < Ci; ci += 64) {
        const float* p = alpha + ((long)co * Ci + ci) * 9;
#pragma unroll
        for (int k = 0; k < 9; k++) acc[k] += 1.f / (1.f + expf(p[k]));
    }
#pragma unroll
    for (int k = 0; k < 9; k++) {
        for (int off = 32; off > 0; off >>= 1) acc[k] += __shfl_down(acc[k], off);
    }
    if (lane == 0) {
#pragma unroll
        for (int k = 0; k < 9; k++) s[co * 9 + k] = acc[k];
    }
}

// ones_grid[co][y][x] = sum over valid (ky,kx) of ssum[co][ky*3+kx]
__global__ void prep_ones(const float* __restrict__ ssum, float* __restrict__ og,
                          int Co, int Hout, int Wout, int Hin, int Win, int stride, int total) {
    int idx = blockIdx.x * 256 + threadIdx.x;
    if (idx >= total) return;
    int x = idx % Wout, y = (idx / Wout) % Hout, co = idx / (Wout * Hout);
    float s = 0.f;
    for (int ky = 0; ky < 3; ky++) {
        int yi = stride * y - 1 + ky;
        if (yi < 0 || yi >= Hin) continue;
        for (int kx = 0; kx < 3; kx++) {
            int xi = stride * x - 1 + kx;
            if (xi < 0 || xi >= Win) continue;
            s += ssum[co * 9 + ky * 3 + kx];
        }
    }
    og[idx] = s;
}

// ---------------------------------------------------------------------------
// L1: fp32 vector conv (Ci=3) -> erf -> NHWC bf16. One block per (b,y).
// ---------------------------------------------------------------------------
__global__ __launch_bounds__(256) void conv1_k(const float* __restrict__ x,
        const float* __restrict__ wa, const float* __restrict__ wb,
        const float* __restrict__ bias, unsigned short* __restrict__ out) {
    __shared__ float win[3 * 102];       // [ci][3 rows][34]
    __shared__ float wl[2][128 * 28];
    int b = blockIdx.x >> 5;
    int y = blockIdx.x & 31;
    int tid = threadIdx.x;
    for (int i = tid; i < 306; i += 256) {
        int ci = i / 102, r = (i % 102) / 34, px = i % 34;
        int yy = y - 1 + r, xx = px - 1;
        float v = 0.f;
        if (yy >= 0 && yy < 32 && xx >= 0 && xx < 32)
            v = x[((b * 3 + ci) * 32 + yy) * 32 + xx];
        win[i] = v;
    }
    for (int i = tid; i < 128 * 27; i += 256) {
        int co = i / 27, j = i % 27;
        wl[0][co * 28 + j] = wa[i];
        wl[1][co * 28 + j] = wb[i];
    }
    __syncthreads();
    int xo = tid >> 3;
    int cb = (tid & 7) * 16;
    float iv[27], sq[27];
#pragma unroll
    for (int ci = 0; ci < 3; ci++)
#pragma unroll
    for (int ky = 0; ky < 3; ky++)
#pragma unroll
    for (int kx = 0; kx < 3; kx++) {
        float v = win[ci * 102 + ky * 34 + xo + kx];
        iv[ci * 9 + ky * 3 + kx] = v;
        sq[ci * 9 + ky * 3 + kx] = v * v;
    }
    unsigned int pk[8];
#pragma unroll
    for (int k = 0; k < 16; k++) {
        int co = cb + k;
        float m = bias[co], vv = 0.f;
#pragma unroll
        for (int j = 0; j < 27; j++) {
            m = fmaf(iv[j], wl[0][co * 28 + j], m);
            vv = fmaf(sq[j], wl[1][co * 28 + j], vv);
        }
        unsigned int hv = f2bf(erff(m * rsqrtf(vv + EPSV) * INV_SQRT2));
        if (k & 1) pk[k >> 1] |= hv << 16; else pk[k >> 1] = hv;
    }
    long oa = (((long)b * 32 + y) * 32 + xo) * 128 + cb;
    uint4 u0; u0.x = pk[0]; u0.y = pk[1]; u0.z = pk[2]; u0.w = pk[3];
    uint4 u1; u1.x = pk[4]; u1.y = pk[5]; u1.z = pk[6]; u1.w = pk[7];
    *(uint4*)(out + oa) = u0;
    *(uint4*)(out + oa + 8) = u1;
}

// ---------------------------------------------------------------------------
// MFMA implicit-GEMM fused LRnet conv. NHWC bf16 input.
// MODE 0: lrconv  -> erf -> NHWC bf16      (v = convB)
// MODE 1: ver2    -> erf -> NHWC bf16      (v = ones - convB)
// MODE 2: ver2 + sample -> NCHW fp32       (out = m + sqrt(v+eps)*epsb)
// ---------------------------------------------------------------------------
template<int Ci, int Hin, int Win, int Co, int Hout, int Wout, int STRIDE,
         int ROWS, int IPB, int NTILE, int MODE>
__global__ __launch_bounds__(256, 2) void conv_mfma(
    const unsigned short* __restrict__ in,
    const unsigned short* __restrict__ wpk,
    const float* __restrict__ bias,
    const float* __restrict__ ones_g,
    const float* __restrict__ epsb,
    void* __restrict__ outp)
{
    constexpr int MTILE = 128;
    constexpr int PROWS = STRIDE * (ROWS - 1) + 3;
    constexpr int PW = Win + 2;
    constexpr int POS = IPB * PROWS * PW;
    constexpr int NCH = Ci / 32;
    constexpr int MFg = Co / 16;
    constexpr int NF = NTILE / 16;
    constexpr int WMF = 4;
    constexpr int WNF = NF / 2;
    constexpr int CT = Co / MTILE;
    constexpr int RG = Hout / ROWS;
    constexpr int LINE = 80;               // bytes per position per array
    constexpr int XS = POS * LINE;         // x^2 array offset
    constexpr int TSTR = MTILE + 8;
    constexpr int STAGE_B = 2 * POS * LINE;
    constexpr int TR_B = (MODE == 2) ? 0 : NTILE * TSTR * 2;
    constexpr int LDS_B = STAGE_B > TR_B ? STAGE_B : TR_B;
    __shared__ char lds[LDS_B];

    const int tid = threadIdx.x;
    const int lane = tid & 63;
    const int wv = tid >> 6;
    const int wm = wv & 1, wn = wv >> 1;
    const int g = lane >> 4, ln = lane & 15;

    const int bid = blockIdx.x;
    const int ct = bid % CT;
    const int nt = bid / CT;
    const int b0 = (nt / RG) * IPB;
    const int y0 = (nt % RG) * ROWS;

    int pbase[WNF];
#pragma unroll
    for (int nf = 0; nf < WNF; nf++) {
        int n = (wn * WNF + nf) * 16 + ln;
        int img = n / (ROWS * Wout);
        int rem = n % (ROWS * Wout);
        int yr = rem / Wout, xo = rem % Wout;
        pbase[nf] = (img * PROWS + STRIDE * yr) * PW + STRIDE * xo;
    }

    f32x4 accA[WMF][WNF], accB[WMF][WNF];
#pragma unroll
    for (int mf = 0; mf < WMF; mf++)
#pragma unroll
    for (int nf = 0; nf < WNF; nf++) {
        accA[mf][nf] = (f32x4){0.f, 0.f, 0.f, 0.f};
        accB[mf][nf] = (f32x4){0.f, 0.f, 0.f, 0.f};
    }

    const unsigned short* wbase = wpk + ((long)(ct * 8 + wm * WMF) * 64 + lane) * 8;

    for (int ch = 0; ch < NCH; ch++) {
        // ---- stage x, x^2 (bf16) into LDS ----
        for (int i = tid; i < POS * 4; i += 256) {
            int p = i >> 2, c = i & 3;
            int img = p / (PROWS * PW);
            int r = p % (PROWS * PW);
            int prow = r / PW, px = r % PW;
            int yin = STRIDE * y0 - 1 + prow;
            int xin = px - 1;
            uint4 v; v.x = 0; v.y = 0; v.z = 0; v.w = 0;
            if (yin >= 0 && yin < Hin && xin >= 0 && xin < Win) {
                long a = (((long)(b0 + img) * Hin + yin) * Win + xin) * Ci + ch * 32 + c * 8;
                v = *(const uint4*)(in + a);
            }
            *(uint4*)(lds + p * LINE + c * 16) = v;
            uint4 s;
            unsigned int* vp = (unsigned int*)&v;
            unsigned int* sp = (unsigned int*)&s;
#pragma unroll
            for (int e = 0; e < 4; e++) {
                float lo = bf2f((unsigned short)(vp[e] & 0xffffu));
                float hi = bf2f((unsigned short)(vp[e] >> 16));
                sp[e] = (unsigned int)f2bf(lo * lo) | (((unsigned int)f2bf(hi * hi)) << 16);
            }
            *(uint4*)(lds + XS + p * LINE + c * 16) = s;
        }
        __syncthreads();
        // ---- 9 kernel positions ----
#pragma unroll 3
        for (int pos = 0; pos < 9; pos++) {
            const int ky = pos / 3, kx = pos % 3;
            short8 af[2][WMF];
#pragma unroll
            for (int cv = 0; cv < 2; cv++)
#pragma unroll
            for (int mf = 0; mf < WMF; mf++)
                af[cv][mf] = *(const short8*)(wbase +
                    ((long)(((cv * 9 + pos) * NCH + ch) * MFg + mf)) * 512);
            short8 bx[WNF], bq[WNF];
#pragma unroll
            for (int nf = 0; nf < WNF; nf++) {
                int po = (pbase[nf] + ky * PW + kx) * LINE + g * 16;
                bx[nf] = *(const short8*)(lds + po);
                bq[nf] = *(const short8*)(lds + XS + po);
            }
#pragma unroll
            for (int mf = 0; mf < WMF; mf++)
#pragma unroll
            for (int nf = 0; nf < WNF; nf++) {
                accA[mf][nf] = __builtin_amdgcn_mfma_f32_16x16x32_bf16(af[0][mf], bx[nf], accA[mf][nf], 0, 0, 0);
                accB[mf][nf] = __builtin_amdgcn_mfma_f32_16x16x32_bf16(af[1][mf], bq[nf], accB[mf][nf], 0, 0, 0);
            }
        }
        __syncthreads();
    }

    // ---- epilogue ----
    if constexpr (MODE == 2) {
        float* out = (float*)outp;
#pragma unroll
        for (int mf = 0; mf < WMF; mf++) {
            int co = ct * MTILE + (wm * WMF + mf) * 16 + g * 4;
#pragma unroll
            for (int nf = 0; nf < WNF; nf++) {
                int n = (wn * WNF + nf) * 16 + ln;
                int img = n / (ROWS * Wout), rem = n % (ROWS * Wout);
                int y = y0 + rem / Wout, x = rem % Wout;
                int b = b0 + img;
#pragma unroll
                for (int r = 0; r < 4; r++) {
                    int c = co + r;
                    float m = accA[mf][nf][r] + bias[c];
                    float v = ones_g[(c * Hout + y) * Wout + x] - accB[mf][nf][r];
                    long oi = (((long)b * Co + c) * Hout + y) * Wout + x;
                    out[oi] = m + sqrtf(v + EPSV) * epsb[oi];
                }
            }
        }
    } else {
        unsigned short* out = (unsigned short*)outp;
#pragma unroll
        for (int mf = 0; mf < WMF; mf++) {
            int cob = (wm * WMF + mf) * 16 + g * 4;
            int cg = ct * MTILE + cob;
#pragma unroll
            for (int nf = 0; nf < WNF; nf++) {
                int n = (wn * WNF + nf) * 16 + ln;
                int img = n / (ROWS * Wout), rem = n % (ROWS * Wout);
                int y = y0 + rem / Wout, x = rem % Wout;
                unsigned int pk2[2];
#pragma unroll
                for (int r = 0; r < 4; r++) {
                    int c = cg + r;
                    float m = accA[mf][nf][r] + bias[c];
                    float v;
                    if constexpr (MODE == 1)
                        v = ones_g[(c * Hout + y) * Wout + x] - accB[mf][nf][r];
                    else
                        v = accB[mf][nf][r];
                    unsigned int hv = f2bf(erff(m * rsqrtf(v + EPSV) * INV_SQRT2));
                    if (r & 1) pk2[r >> 1] |= hv << 16; else pk2[r >> 1] = hv;
                }
                *(unsigned int*)(lds + (n * TSTR + cob) * 2) = pk2[0];
                *(unsigned int*)(lds + (n * TSTR + cob) * 2 + 4) = pk2[1];
            }
        }
        __syncthreads();
        for (int i = tid; i < NTILE * (MTILE / 8); i += 256) {
            int n = i / (MTILE / 8);
            int c8 = (i % (MTILE / 8)) * 8;
            int img = n / (ROWS * Wout), rem = n % (ROWS * Wout);
            int y = y0 + rem / Wout, x = rem % Wout;
            int b = b0 + img;
            uint4 val = *(const uint4*)(lds + (n * TSTR + c8) * 2);
            long oa = (((long)b * Hout + y) * Wout + x) * Co + ct * MTILE + c8;
            *(uint4*)(out + oa) = val;
        }
    }
}

// ---------------------------------------------------------------------------
// BatchNorm
// ---------------------------------------------------------------------------
__global__ void bn_stats(const float* __restrict__ h, float* __restrict__ st,
                         int C, int HW, int Bchunk) {
    int c = blockIdx.x;
    int chunk = blockIdx.y;
    int tid = threadIdx.x;
    float s = 0.f, s2 = 0.f;
    int total = Bchunk * HW;
    int bbase = chunk * Bchunk;
    for (int j = tid; j < total; j += 256) {
        int b = bbase + j / HW;
        int i = j % HW;
        float v = h[((long)b * C + c) * HW + i];
        s += v; s2 += v * v;
    }
    for (int off = 32; off > 0; off >>= 1) {
        s += __shfl_down(s, off);
        s2 += __shfl_down(s2, off);
    }
    __shared__ float red[8];
    int wid = tid >> 6, lane = tid & 63;
    if (lane == 0) { red[wid] = s; red[4 + wid] = s2; }
    __syncthreads();
    if (tid == 0) {
        atomicAdd(&st[c], red[0] + red[1] + red[2] + red[3]);
        atomicAdd(&st[C + c], red[4] + red[5] + red[6] + red[7]);
    }
}

// h6 in-place NCHW fp32 BN+relu
__global__ void bn_apply(float* __restrict__ h, const float* __restrict__ st,
                         const float* __restrict__ gamma, const float* __restrict__ beta,
                         int C, int HW, long N, float invN) {
    for (long idx = (long)blockIdx.x * blockDim.x + threadIdx.x; idx < N;
         idx += (long)gridDim.x * blockDim.x) {
        int c = (int)((idx / HW) % C);
        float mean = st[c] * invN;
        float var = st[C + c] * invN - mean * mean;
        float v = gamma[c] * (h[idx] - mean) * rsqrtf(var + BNEPS) + beta[c];
        h[idx] = v > 0.f ? v : 0.f;
    }
}

// h3: NCHW fp32 -> BN+relu -> NHWC bf16 (block per (b,y), C=256, W=16)
__global__ __launch_bounds__(256) void bn_apply_t(const float* __restrict__ h,
        const float* __restrict__ st, const float* __restrict__ gamma,
        const float* __restrict__ beta, unsigned short* __restrict__ out) {
    __shared__ float t[256 * 17];
    int b = blockIdx.x >> 4, y = blockIdx.x & 15;
    int tid = threadIdx.x;
    const float invN = 1.f / 65536.f;
    for (int i = tid; i < 4096; i += 256) {
        int c = i >> 4, xx = i & 15;
        float mean = st[c] * invN;
        float var = st[256 + c] * invN - mean * mean;
        float v = h[(((long)b * 256 + c) * 16 + y) * 16 + xx];
        v = gamma[c] * (v - mean) * rsqrtf(var + BNEPS) + beta[c];
        t[c * 17 + xx] = v > 0.f ? v : 0.f;
    }
    __syncthreads();
    for (int i = tid; i < 4096; i += 256) {
        int xx = i >> 8, c = i & 255;
        out[(((long)b * 16 + y) * 16 + xx) * 256 + c] = f2bf(t[c * 17 + xx]);
    }
}

// ---------------------------------------------------------------------------
// FC1: out[256,1024] = relu(A[256,8192] @ W[1024,8192]^T + b)
// ---------------------------------------------------------------------------
__global__ __launch_bounds__(256) void fc1_k(const float* __restrict__ A,
                                             const float* __restrict__ W,
                                             const float* __restrict__ bias,
                                             float* __restrict__ out) {
    __shared__ float As[32][66];
    __shared__ float Ws[32][66];
    int tid = threadIdx.x;
    int tx = tid % 16, ty = tid / 16;
    int ob = blockIdx.y * 32;
    int oo = blockIdx.x * 32;
    float acc00 = 0.f, acc01 = 0.f, acc10 = 0.f, acc11 = 0.f;
    for (int k0 = 0; k0 < 8192; k0 += 64) {
        for (int i = tid; i < 512; i += 256) {
            int r = i / 16, q = i % 16;
            float4 av = *(const float4*)&A[(long)(ob + r) * 8192 + k0 + q * 4];
            As[r][q * 4 + 0] = av.x; As[r][q * 4 + 1] = av.y;
            As[r][q * 4 + 2] = av.z; As[r][q * 4 + 3] = av.w;
            float4 wv = *(const float4*)&W[(long)(oo + r) * 8192 + k0 + q * 4];
            Ws[r][q * 4 + 0] = wv.x; Ws[r][q * 4 + 1] = wv.y;
            Ws[r][q * 4 + 2] = wv.z; Ws[r][q * 4 + 3] = wv.w;
        }
        __syncthreads();
#pragma unroll
        for (int kk = 0; kk < 64; kk++) {
            float a0 = As[ty * 2][kk], a1 = As[ty * 2 + 1][kk];
            float w0 = Ws[tx * 2][kk], w1 = Ws[tx * 2 + 1][kk];
            acc00 = fmaf(a0, w0, acc00); acc01 = fmaf(a0, w1, acc01);
            acc10 = fmaf(a1, w0, acc10); acc11 = fmaf(a1, w1, acc11);
        }
        __syncthreads();
    }
    float b0 = bias[oo + tx * 2], b1 = bias[oo + tx * 2 + 1];
    float v;
    v = acc00 + b0; out[(long)(ob + ty * 2) * 1024 + oo + tx * 2] = v > 0.f ? v : 0.f;
    v = acc01 + b1; out[(long)(ob + ty * 2) * 1024 + oo + tx * 2 + 1] = v > 0.f ? v : 0.f;
    v = acc10 + b0; out[(long)(ob + ty * 2 + 1) * 1024 + oo + tx * 2] = v > 0.f ? v : 0.f;
    v = acc11 + b1; out[(long)(ob + ty * 2 + 1) * 1024 + oo + tx * 2 + 1] = v > 0.f ? v : 0.f;
}

__global__ void fc2_k(const float* __restrict__ A, const float* __restrict__ W,
                      const float* __restrict__ b2, float* __restrict__ out) {
    int bb = blockIdx.x;
    int tid = threadIdx.x;
    float acc[10];
#pragma unroll
    for (int o = 0; o < 10; o++) acc[o] = 0.f;
    const float* arow = A + (long)bb * 1024;
    for (int k = tid; k < 1024; k += 256) {
        float a = arow[k];
#pragma unroll
        for (int o = 0; o < 10; o++) acc[o] = fmaf(a, W[o * 1024 + k], acc[o]);
    }
#pragma unroll
    for (int o = 0; o < 10; o++)
        for (int off = 32; off > 0; off >>= 1) acc[o] += __shfl_down(acc[o], off);
    __shared__ float red[10][4];
    int wid = tid >> 6, lane = tid & 63;
    if (lane == 0) {
#pragma unroll
        for (int o = 0; o < 10; o++) red[o][wid] = acc[o];
    }
    __syncthreads();
    if (tid < 10)
        out[bb * 10 + tid] = red[tid][0] + red[tid][1] + red[tid][2] + red[tid][3] + b2[tid];
}

// ---------------------------------------------------------------------------
extern "C" void kernel_launch(void* const* d_in, const int* in_sizes, int n_in,
                              void* d_out, int out_size, void* d_ws, size_t ws_size,
                              hipStream_t stream) {
    const float* x  = (const float*)d_in[0];
    const float* a1 = (const float*)d_in[1];  const float* b1 = (const float*)d_in[2];  const float* c1 = (const float*)d_in[3];
    const float* a2 = (const float*)d_in[4];  const float* b2 = (const float*)d_in[5];  const float* c2 = (const float*)d_in[6];
    const float* a3 = (const float*)d_in[7];  const float* b3 = (const float*)d_in[8];  const float* c3 = (const float*)d_in[9];
    const float* a4 = (const float*)d_in[10]; const float* b4 = (const float*)d_in[11]; const float* c4 = (const float*)d_in[12];
    const float* a5 = (const float*)d_in[13]; const float* b5 = (const float*)d_in[14]; const float* c5 = (const float*)d_in[15];
    const float* a6 = (const float*)d_in[16]; const float* b6 = (const float*)d_in[17]; const float* c6 = (const float*)d_in[18];
    const float* g3 = (const float*)d_in[19]; const float* be3 = (const float*)d_in[20];
    const float* g6 = (const float*)d_in[21]; const float* be6 = (const float*)d_in[22];
    const float* fc1w = (const float*)d_in[23]; const float* fc1b = (const float*)d_in[24];
    const float* fc2w = (const float*)d_in[25]; const float* fc2b = (const float*)d_in[26];
    const float* eps3 = (const float*)d_in[27]; const float* eps6 = (const float*)d_in[28];
    (void)in_sizes; (void)n_in; (void)out_size; (void)ws_size;

    float* w = (float*)d_ws;
    size_t off = 0;
    auto alloc = [&](size_t n) { float* p = w + off; off += n; return p; };
    unsigned short* pk2 = (unsigned short*)alloc(147456);
    unsigned short* pk3 = (unsigned short*)alloc(294912);
    unsigned short* pk4 = (unsigned short*)alloc(589824);
    unsigned short* pk5 = (unsigned short*)alloc(1179648);
    unsigned short* pk6 = (unsigned short*)alloc(2359296);
    float* wa1 = alloc(3456); float* wb1 = alloc(3456);
    float* ss2 = alloc(1152); float* ss3 = alloc(2304);
    float* ss5 = alloc(4608); float* ss6 = alloc(4608);
    float* og2 = alloc(32768); float* og3 = alloc(65536);
    float* og5 = alloc(32768); float* og6 = alloc(8192);
    float* st3 = alloc(512);  float* st6 = alloc(1024);
    float* A  = alloc(16777216);  // ex1 (bf16) -> h3 (f32)
    float* Bb = alloc(4194304);   // ex2 (bf16) -> fco (f32)
    float* Cc = alloc(8388608);   // h3t (bf16) -> h6 (f32)
    float* Dd = alloc(2097152);   // ex4 (bf16)
    float* Ee = alloc(4194304);   // ex5 (bf16)

    unsigned short* ex1 = (unsigned short*)A;
    float*          h3  = A;
    unsigned short* ex2 = (unsigned short*)Bb;
    float*          fco = Bb;
    unsigned short* h3t = (unsigned short*)Cc;
    float*          h6  = Cc;
    unsigned short* ex4 = (unsigned short*)Dd;
    unsigned short* ex5 = (unsigned short*)Ee;

    // ---- prep ----
    prep_w<<<14, 256, 0, stream>>>(a1, b1, wa1, wb1, 3456);
    prep_pack<<<72,  256, 0, stream>>>(a2, b2, pk2, 128, 128, 1, 18432);
    prep_pack<<<144, 256, 0, stream>>>(a3, b3, pk3, 128, 256, 1, 36864);
    prep_pack<<<288, 256, 0, stream>>>(a4, b4, pk4, 256, 256, 0, 73728);
    prep_pack<<<576, 256, 0, stream>>>(a5, b5, pk5, 256, 512, 1, 147456);
    prep_pack<<<1152,256, 0, stream>>>(a6, b6, pk6, 512, 512, 1, 294912);
    prep_s<<<128, 64, 0, stream>>>(a2, ss2, 128);
    prep_s<<<256, 64, 0, stream>>>(a3, ss3, 128);
    prep_s<<<512, 64, 0, stream>>>(a5, ss5, 256);
    prep_s<<<512, 64, 0, stream>>>(a6, ss6, 512);
    prep_ones<<<128, 256, 0, stream>>>(ss2, og2, 128, 16, 16, 32, 32, 2, 32768);
    prep_ones<<<256, 256, 0, stream>>>(ss3, og3, 256, 16, 16, 16, 16, 1, 65536);
    prep_ones<<<128, 256, 0, stream>>>(ss5, og5, 512, 8, 8, 8, 8, 1, 32768);
    prep_ones<<<32,  256, 0, stream>>>(ss6, og6, 512, 4, 4, 8, 8, 2, 8192);

    // ---- network ----
    conv1_k<<<8192, 256, 0, stream>>>(x, wa1, wb1, c1, ex1);
    // L2: [256,32,32,128] -> [256,16,16,128]
    conv_mfma<128,32,32,128,16,16,2, 8,1,128,1><<<512, 256, 0, stream>>>(ex1, pk2, c2, og2, nullptr, ex2);
    // L3: -> h3 [256,256,16,16] NCHW f32 (sampled)
    conv_mfma<128,16,16,256,16,16,1, 8,1,128,2><<<1024, 256, 0, stream>>>(ex2, pk3, c3, og3, eps3, h3);
    // BN3 + relu + transpose to NHWC bf16
    hipMemsetAsync(st3, 0, 512 * sizeof(float), stream);
    bn_stats<<<dim3(256, 8), 256, 0, stream>>>(h3, st3, 256, 256, 32);
    bn_apply_t<<<4096, 256, 0, stream>>>(h3, st3, g3, be3, h3t);
    // L4: [256,16,16,256] -> [256,8,8,256]
    conv_mfma<256,16,16,256, 8, 8,2, 8,2,128,0><<<256, 256, 0, stream>>>(h3t, pk4, c4, nullptr, nullptr, ex4);
    // L5: -> [256,8,8,512]
    conv_mfma<256, 8, 8,512, 8, 8,1, 8,2,128,1><<<512, 256, 0, stream>>>(ex4, pk5, c5, og5, nullptr, ex5);
    // L6: -> h6 [256,512,4,4] NCHW f32 (sampled)
    conv_mfma<512, 8, 8,512, 4, 4,2, 4,4, 64,2><<<256, 256, 0, stream>>>(ex5, pk6, c6, og6, eps6, h6);
    // BN6 + relu (in place)
    hipMemsetAsync(st6, 0, 1024 * sizeof(float), stream);
    bn_stats<<<dim3(512, 8), 256, 0, stream>>>(h6, st6, 512, 16, 32);
    bn_apply<<<2048, 256, 0, stream>>>(h6, st6, g6, be6, 512, 16, (long)256 * 512 * 16, 1.f / 4096.f);
    // FC
    fc1_k<<<dim3(32, 8), 256, 0, stream>>>(h6, fc1w, fc1b, fco);
    fc2_k<<<256, 256, 0, stream>>>(fco, fc2w, fc2b, (float*)d_out);
}

// Round 3
// 1272.241 us; speedup vs baseline: 4.4600x; 1.2519x over previous
//
#include <hip/hip_runtime.h>
#include <hip/hip_bf16.h>
#include <math.h>

#define EPSV 1e-10f
#define BNEPS 1e-5f
#define INV_SQRT2 0.70710678118654752440f

typedef __attribute__((ext_vector_type(8))) short short8;
typedef __attribute__((ext_vector_type(4))) float f32x4;

__device__ __forceinline__ float bf2f(unsigned short u) {
    union { unsigned int i; float f; } c; c.i = ((unsigned int)u) << 16; return c.f;
}
__device__ __forceinline__ unsigned short f2bf(float f) {
    unsigned int u = __float_as_uint(f);
    return (unsigned short)((u + 0x7FFFu + ((u >> 16) & 1u)) >> 16);
}

// ---------------------------------------------------------------------------
// L1 weight prep (fp32, OIHW kept): e_w and var_w
// ---------------------------------------------------------------------------
__global__ void prep_w(const float* __restrict__ a, const float* __restrict__ b,
                       float* __restrict__ WA, float* __restrict__ WB, int n) {
    for (int i = blockIdx.x * blockDim.x + threadIdx.x; i < n; i += gridDim.x * blockDim.x) {
        float p0 = 1.f / (1.f + expf(-a[i]));
        float sb = 1.f / (1.f + expf(-b[i]));
        float p1 = (1.f - p0) * sb;
        float ew = 2.f * p1 - (1.f - p0);
        float ew2 = 1.f - p0;
        WA[i] = ew;
        WB[i] = ew2 - ew * ew;
    }
}

// ---------------------------------------------------------------------------
// Pack ternary-stat weights into MFMA A-fragment order (bf16).
// index: ((((cv*9+pos)*NCH + ch)*MFg + mf)*64 + lane)*8 + j
//   co = mf*16 + (lane&15), ci = ch*32 + (lane>>4)*8 + j
// cv=0 -> e_w ; cv=1 -> (ver2 ? e_w^2 : var_w)
// ---------------------------------------------------------------------------
__global__ void prep_pack(const float* __restrict__ a, const float* __restrict__ b,
                          unsigned short* __restrict__ pk, int Ci, int Co, int ver2, int total) {
    int idx = blockIdx.x * 256 + threadIdx.x;
    if (idx >= total) return;
    int lane = idx & 63;
    int MFg = Co >> 4, NCH = Ci >> 5;
    int mfch = idx >> 6;
    int mf = mfch % MFg;
    int chpos = mfch / MFg;
    int ch = chpos % NCH;
    int pos = chpos / NCH;
    int co = mf * 16 + (lane & 15);
    int cib = ch * 32 + (lane >> 4) * 8;
    unsigned int wa[4], wb[4];
#pragma unroll
    for (int j = 0; j < 8; j++) {
        long s = ((long)co * Ci + cib + j) * 9 + pos;
        float p0 = 1.f / (1.f + expf(-a[s]));
        float sb = 1.f / (1.f + expf(-b[s]));
        float p1 = (1.f - p0) * sb;
        float ew = 2.f * p1 - (1.f - p0);
        float ew2 = 1.f - p0;
        unsigned int ha = f2bf(ew);
        unsigned int hb = f2bf(ver2 ? ew * ew : ew2 - ew * ew);
        if (j & 1) { wa[j >> 1] |= ha << 16; wb[j >> 1] |= hb << 16; }
        else       { wa[j >> 1] = ha;        wb[j >> 1] = hb; }
    }
    long b0 = (((long)(0 * 9 + pos) * NCH + ch) * MFg + mf) * 64 + lane;
    long b1 = (((long)(1 * 9 + pos) * NCH + ch) * MFg + mf) * 64 + lane;
    uint4 va; va.x = wa[0]; va.y = wa[1]; va.z = wa[2]; va.w = wa[3];
    uint4 vb; vb.x = wb[0]; vb.y = wb[1]; vb.z = wb[2]; vb.w = wb[3];
    *(uint4*)(pk + b0 * 8) = va;
    *(uint4*)(pk + b1 * 8) = vb;
}

// ssum[co][k] = sum_ci sigmoid(-alpha)   (= sum_ci E[w^2])
__global__ void prep_s(const float* __restrict__ alpha, float* __restrict__ s, int Ci) {
    int co = blockIdx.x;
    int lane = threadIdx.x; // 64
    float acc[9];
#pragma unroll
    for (int k = 0; k < 9; k++) acc[k] = 0.f;
    for (int ci = lane; ci < Ci; ci += 64) {
        const float* p = alpha + ((long)co * Ci + ci) * 9;
#pragma unroll
        for (int k = 0; k < 9; k++) acc[k] += 1.f / (1.f + expf(p[k]));
    }
#pragma unroll
    for (int k = 0; k < 9; k++) {
        for (int off = 32; off > 0; off >>= 1) acc[k] += __shfl_down(acc[k], off);
    }
    if (lane == 0) {
#pragma unroll
        for (int k = 0; k < 9; k++) s[co * 9 + k] = acc[k];
    }
}

// ones_grid[co][y][x] = sum over valid (ky,kx) of ssum[co][ky*3+kx]
__global__ void prep_ones(const float* __restrict__ ssum, float* __restrict__ og,
                          int Co, int Hout, int Wout, int Hin, int Win, int stride, int total) {
    int idx = blockIdx.x * 256 + threadIdx.x;
    if (idx >= total) return;
    int x = idx % Wout, y = (idx / Wout) % Hout, co = idx / (Wout * Hout);
    float s = 0.f;
    for (int ky = 0; ky < 3; ky++) {
        int yi = stride * y - 1 + ky;
        if (yi < 0 || yi >= Hin) continue;
        for (int kx = 0; kx < 3; kx++) {
            int xi = stride * x - 1 + kx;
            if (xi < 0 || xi >= Win) continue;
            s += ssum[co * 9 + ky * 3 + kx];
        }
    }
    og[idx] = s;
}

// ---------------------------------------------------------------------------
// L1: fp32 vector conv (Ci=3) -> erf -> NHWC bf16.
// Block = (b, 2 rows); 256 thr = 32 xo * 8 co-groups.
// Weight reads uniform per half-wave (broadcast); window reads stride-1.
// ---------------------------------------------------------------------------
__global__ __launch_bounds__(256) void conv1_k(const float* __restrict__ x,
        const float* __restrict__ wa, const float* __restrict__ wb,
        const float* __restrict__ bias, unsigned short* __restrict__ out) {
    __shared__ float win[3 * 4 * 34];          // [ci][4 rows][34]
    __shared__ float wl[128 * 56];             // [co][28][(wa,wb)] interleaved
    int b = blockIdx.x >> 4;
    int y0 = (blockIdx.x & 15) * 2;
    int tid = threadIdx.x;
    for (int i = tid; i < 408; i += 256) {
        int ci = i / 136, r = (i % 136) / 34, px = i % 34;
        int yy = y0 - 1 + r, xx = px - 1;
        float v = 0.f;
        if (yy >= 0 && yy < 32 && xx >= 0 && xx < 32)
            v = x[((b * 3 + ci) * 32 + yy) * 32 + xx];
        win[i] = v;
    }
    for (int i = tid; i < 128 * 56; i += 256) {
        int co = i / 56, q = i % 56, j = q >> 1;
        float v = 0.f;
        if (j < 27) v = (q & 1) ? wb[co * 27 + j] : wa[co * 27 + j];
        wl[i] = v;
    }
    __syncthreads();
    int xo = tid & 31;
    int cog = tid >> 5;
    float iv[2][28], sq[2][28];
#pragma unroll
    for (int r = 0; r < 2; r++) {
#pragma unroll
        for (int ci = 0; ci < 3; ci++)
#pragma unroll
        for (int ky = 0; ky < 3; ky++)
#pragma unroll
        for (int kx = 0; kx < 3; kx++) {
            float v = win[(ci * 4 + r + ky) * 34 + xo + kx];
            iv[r][ci * 9 + ky * 3 + kx] = v;
            sq[r][ci * 9 + ky * 3 + kx] = v * v;
        }
        iv[r][27] = 0.f; sq[r][27] = 0.f;
    }
    unsigned int pk[2][8];
#pragma unroll
    for (int k = 0; k < 16; k++) {
        int co = cog * 16 + k;
        const float4* wp = (const float4*)&wl[co * 56];
        float bs = bias[co];
        float m0 = bs, v0 = 0.f, m1 = bs, v1 = 0.f;
#pragma unroll
        for (int q = 0; q < 14; q++) {
            float4 w4 = wp[q];
            m0 = fmaf(iv[0][2 * q], w4.x, m0);     v0 = fmaf(sq[0][2 * q], w4.y, v0);
            m0 = fmaf(iv[0][2 * q + 1], w4.z, m0); v0 = fmaf(sq[0][2 * q + 1], w4.w, v0);
            m1 = fmaf(iv[1][2 * q], w4.x, m1);     v1 = fmaf(sq[1][2 * q], w4.y, v1);
            m1 = fmaf(iv[1][2 * q + 1], w4.z, m1); v1 = fmaf(sq[1][2 * q + 1], w4.w, v1);
        }
        unsigned int h0 = f2bf(erff(m0 * rsqrtf(v0 + EPSV) * INV_SQRT2));
        unsigned int h1 = f2bf(erff(m1 * rsqrtf(v1 + EPSV) * INV_SQRT2));
        if (k & 1) { pk[0][k >> 1] |= h0 << 16; pk[1][k >> 1] |= h1 << 16; }
        else       { pk[0][k >> 1] = h0;        pk[1][k >> 1] = h1; }
    }
#pragma unroll
    for (int r = 0; r < 2; r++) {
        long oa = (((long)b * 32 + y0 + r) * 32 + xo) * 128 + cog * 16;
        uint4 u0; u0.x = pk[r][0]; u0.y = pk[r][1]; u0.z = pk[r][2]; u0.w = pk[r][3];
        uint4 u1; u1.x = pk[r][4]; u1.y = pk[r][5]; u1.z = pk[r][6]; u1.w = pk[r][7];
        *(uint4*)(out + oa) = u0;
        *(uint4*)(out + oa + 8) = u1;
    }
}

// ---------------------------------------------------------------------------
// MFMA implicit-GEMM fused LRnet conv. NHWC bf16 input.
// MODE 0: lrconv  -> erf -> NHWC bf16      (v = convB)
// MODE 1: ver2    -> erf -> NHWC bf16      (v = ones - convB)
// MODE 2: ver2 + sample -> NCHW fp32       (out = m + sqrt(v+eps)*epsb)
// ---------------------------------------------------------------------------
template<int Ci, int Hin, int Win, int Co, int Hout, int Wout, int STRIDE,
         int ROWS, int IPB, int NTILE, int MODE>
__global__ __launch_bounds__(256, 2) void conv_mfma(
    const unsigned short* __restrict__ in,
    const unsigned short* __restrict__ wpk,
    const float* __restrict__ bias,
    const float* __restrict__ ones_g,
    const float* __restrict__ epsb,
    void* __restrict__ outp)
{
    constexpr int MTILE = 128;
    constexpr int PROWS = STRIDE * (ROWS - 1) + 3;
    constexpr int PW = Win + 2;
    constexpr int POS = IPB * PROWS * PW;
    constexpr int NCH = Ci / 32;
    constexpr int MFg = Co / 16;
    constexpr int NF = NTILE / 16;
    constexpr int WMF = 4;
    constexpr int WNF = NF / 2;
    constexpr int CT = Co / MTILE;
    constexpr int RG = Hout / ROWS;
    constexpr int LINE = 80;               // bytes per position per array
    constexpr int XS = POS * LINE;         // x^2 array offset
    constexpr int TSTR = MTILE + 8;
    constexpr int STAGE_B = 2 * POS * LINE;
    constexpr int TR_B = (MODE == 2) ? 0 : NTILE * TSTR * 2;
    constexpr int LDS_B = STAGE_B > TR_B ? STAGE_B : TR_B;
    __shared__ char lds[LDS_B];

    const int tid = threadIdx.x;
    const int lane = tid & 63;
    const int wv = tid >> 6;
    const int wm = wv & 1, wn = wv >> 1;
    const int g = lane >> 4, ln = lane & 15;

    const int bid = blockIdx.x;
    const int ct = bid % CT;
    const int nt = bid / CT;
    const int b0 = (nt / RG) * IPB;
    const int y0 = (nt % RG) * ROWS;

    int pbase[WNF];
#pragma unroll
    for (int nf = 0; nf < WNF; nf++) {
        int n = (wn * WNF + nf) * 16 + ln;
        int img = n / (ROWS * Wout);
        int rem = n % (ROWS * Wout);
        int yr = rem / Wout, xo = rem % Wout;
        pbase[nf] = (img * PROWS + STRIDE * yr) * PW + STRIDE * xo;
    }

    f32x4 accA[WMF][WNF], accB[WMF][WNF];
#pragma unroll
    for (int mf = 0; mf < WMF; mf++)
#pragma unroll
    for (int nf = 0; nf < WNF; nf++) {
        accA[mf][nf] = (f32x4){0.f, 0.f, 0.f, 0.f};
        accB[mf][nf] = (f32x4){0.f, 0.f, 0.f, 0.f};
    }

    const unsigned short* wbase = wpk + ((long)(ct * 8 + wm * WMF) * 64 + lane) * 8;

    for (int ch = 0; ch < NCH; ch++) {
        // ---- stage x, x^2 (bf16) into LDS ----
        for (int i = tid; i < POS * 4; i += 256) {
            int p = i >> 2, c = i & 3;
            int img = p / (PROWS * PW);
            int r = p % (PROWS * PW);
            int prow = r / PW, px = r % PW;
            int yin = STRIDE * y0 - 1 + prow;
            int xin = px - 1;
            uint4 v; v.x = 0; v.y = 0; v.z = 0; v.w = 0;
            if (yin >= 0 && yin < Hin && xin >= 0 && xin < Win) {
                long a = (((long)(b0 + img) * Hin + yin) * Win + xin) * Ci + ch * 32 + c * 8;
                v = *(const uint4*)(in + a);
            }
            *(uint4*)(lds + p * LINE + c * 16) = v;
            uint4 s;
            unsigned int* vp = (unsigned int*)&v;
            unsigned int* sp = (unsigned int*)&s;
#pragma unroll
            for (int e = 0; e < 4; e++) {
                float lo = bf2f((unsigned short)(vp[e] & 0xffffu));
                float hi = bf2f((unsigned short)(vp[e] >> 16));
                sp[e] = (unsigned int)f2bf(lo * lo) | (((unsigned int)f2bf(hi * hi)) << 16);
            }
            *(uint4*)(lds + XS + p * LINE + c * 16) = s;
        }
        __syncthreads();
        // ---- 9 kernel positions ----
#pragma unroll 3
        for (int pos = 0; pos < 9; pos++) {
            const int ky = pos / 3, kx = pos % 3;
            short8 af[2][WMF];
#pragma unroll
            for (int cv = 0; cv < 2; cv++)
#pragma unroll
            for (int mf = 0; mf < WMF; mf++)
                af[cv][mf] = *(const short8*)(wbase +
                    ((long)(((cv * 9 + pos) * NCH + ch) * MFg + mf)) * 512);
            short8 bx[WNF], bq[WNF];
#pragma unroll
            for (int nf = 0; nf < WNF; nf++) {
                int po = (pbase[nf] + ky * PW + kx) * LINE + g * 16;
                bx[nf] = *(const short8*)(lds + po);
                bq[nf] = *(const short8*)(lds + XS + po);
            }
#pragma unroll
            for (int mf = 0; mf < WMF; mf++)
#pragma unroll
            for (int nf = 0; nf < WNF; nf++) {
                accA[mf][nf] = __builtin_amdgcn_mfma_f32_16x16x32_bf16(af[0][mf], bx[nf], accA[mf][nf], 0, 0, 0);
                accB[mf][nf] = __builtin_amdgcn_mfma_f32_16x16x32_bf16(af[1][mf], bq[nf], accB[mf][nf], 0, 0, 0);
            }
        }
        __syncthreads();
    }

    // ---- epilogue ----
    if constexpr (MODE == 2) {
        float* out = (float*)outp;
#pragma unroll
        for (int mf = 0; mf < WMF; mf++) {
            int co = ct * MTILE + (wm * WMF + mf) * 16 + g * 4;
#pragma unroll
            for (int nf = 0; nf < WNF; nf++) {
                int n = (wn * WNF + nf) * 16 + ln;
                int img = n / (ROWS * Wout), rem = n % (ROWS * Wout);
                int y = y0 + rem / Wout, x = rem % Wout;
                int b = b0 + img;
#pragma unroll
                for (int r = 0; r < 4; r++) {
                    int c = co + r;
                    float m = accA[mf][nf][r] + bias[c];
                    float v = ones_g[(c * Hout + y) * Wout + x] - accB[mf][nf][r];
                    long oi = (((long)b * Co + c) * Hout + y) * Wout + x;
                    out[oi] = m + sqrtf(v + EPSV) * epsb[oi];
                }
            }
        }
    } else {
        unsigned short* out = (unsigned short*)outp;
#pragma unroll
        for (int mf = 0; mf < WMF; mf++) {
            int cob = (wm * WMF + mf) * 16 + g * 4;
            int cg = ct * MTILE + cob;
#pragma unroll
            for (int nf = 0; nf < WNF; nf++) {
                int n = (wn * WNF + nf) * 16 + ln;
                int img = n / (ROWS * Wout), rem = n % (ROWS * Wout);
                int y = y0 + rem / Wout, x = rem % Wout;
                unsigned int pk2[2];
#pragma unroll
                for (int r = 0; r < 4; r++) {
                    int c = cg + r;
                    float m = accA[mf][nf][r] + bias[c];
                    float v;
                    if constexpr (MODE == 1)
                        v = ones_g[(c * Hout + y) * Wout + x] - accB[mf][nf][r];
                    else
                        v = accB[mf][nf][r];
                    unsigned int hv = f2bf(erff(m * rsqrtf(v + EPSV) * INV_SQRT2));
                    if (r & 1) pk2[r >> 1] |= hv << 16; else pk2[r >> 1] = hv;
                }
                *(unsigned int*)(lds + (n * TSTR + cob) * 2) = pk2[0];
                *(unsigned int*)(lds + (n * TSTR + cob) * 2 + 4) = pk2[1];
            }
        }
        __syncthreads();
        for (int i = tid; i < NTILE * (MTILE / 8); i += 256) {
            int n = i / (MTILE / 8);
            int c8 = (i % (MTILE / 8)) * 8;
            int img = n / (ROWS * Wout), rem = n % (ROWS * Wout);
            int y = y0 + rem / Wout, x = rem % Wout;
            int b = b0 + img;
            uint4 val = *(const uint4*)(lds + (n * TSTR + c8) * 2);
            long oa = (((long)b * Hout + y) * Wout + x) * Co + ct * MTILE + c8;
            *(uint4*)(out + oa) = val;
        }
    }
}

// ---------------------------------------------------------------------------
// BatchNorm
// ---------------------------------------------------------------------------
__global__ void bn_stats(const float* __restrict__ h, float* __restrict__ st,
                         int C, int HW, int Bchunk) {
    int c = blockIdx.x;
    int chunk = blockIdx.y;
    int tid = threadIdx.x;
    float s = 0.f, s2 = 0.f;
    int total = Bchunk * HW;
    int bbase = chunk * Bchunk;
    for (int j = tid; j < total; j += 256) {
        int b = bbase + j / HW;
        int i = j % HW;
        float v = h[((long)b * C + c) * HW + i];
        s += v; s2 += v * v;
    }
    for (int off = 32; off > 0; off >>= 1) {
        s += __shfl_down(s, off);
        s2 += __shfl_down(s2, off);
    }
    __shared__ float red[8];
    int wid = tid >> 6, lane = tid & 63;
    if (lane == 0) { red[wid] = s; red[4 + wid] = s2; }
    __syncthreads();
    if (tid == 0) {
        atomicAdd(&st[c], red[0] + red[1] + red[2] + red[3]);
        atomicAdd(&st[C + c], red[4] + red[5] + red[6] + red[7]);
    }
}

// h6 in-place NCHW fp32 BN+relu
__global__ void bn_apply(float* __restrict__ h, const float* __restrict__ st,
                         const float* __restrict__ gamma, const float* __restrict__ beta,
                         int C, int HW, long N, float invN) {
    for (long idx = (long)blockIdx.x * blockDim.x + threadIdx.x; idx < N;
         idx += (long)gridDim.x * blockDim.x) {
        int c = (int)((idx / HW) % C);
        float mean = st[c] * invN;
        float var = st[C + c] * invN - mean * mean;
        float v = gamma[c] * (h[idx] - mean) * rsqrtf(var + BNEPS) + beta[c];
        h[idx] = v > 0.f ? v : 0.f;
    }
}

// h3: NCHW fp32 -> BN+relu -> NHWC bf16 (block per (b,y), C=256, W=16)
__global__ __launch_bounds__(256) void bn_apply_t(const float* __restrict__ h,
        const float* __restrict__ st, const float* __restrict__ gamma,
        const float* __restrict__ beta, unsigned short* __restrict__ out) {
    __shared__ float t[256 * 17];
    int b = blockIdx.x >> 4, y = blockIdx.x & 15;
    int tid = threadIdx.x;
    const float invN = 1.f / 65536.f;
    for (int i = tid; i < 4096; i += 256) {
        int c = i >> 4, xx = i & 15;
        float mean = st[c] * invN;
        float var = st[256 + c] * invN - mean * mean;
        float v = h[(((long)b * 256 + c) * 16 + y) * 16 + xx];
        v = gamma[c] * (v - mean) * rsqrtf(var + BNEPS) + beta[c];
        t[c * 17 + xx] = v > 0.f ? v : 0.f;
    }
    __syncthreads();
    for (int i = tid; i < 4096; i += 256) {
        int xx = i >> 8, c = i & 255;
        out[(((long)b * 16 + y) * 16 + xx) * 256 + c] = f2bf(t[c * 17 + xx]);
    }
}

// ---------------------------------------------------------------------------
// FC1: out[256,1024] = relu(A[256,8192] @ W[1024,8192]^T + b)
// ---------------------------------------------------------------------------
__global__ __launch_bounds__(256) void fc1_k(const float* __restrict__ A,
                                             const float* __restrict__ W,
                                             const float* __restrict__ bias,
                                             float* __restrict__ out) {
    __shared__ float As[32][66];
    __shared__ float Ws[32][66];
    int tid = threadIdx.x;
    int tx = tid % 16, ty = tid / 16;
    int ob = blockIdx.y * 32;
    int oo = blockIdx.x * 32;
    float acc00 = 0.f, acc01 = 0.f, acc10 = 0.f, acc11 = 0.f;
    for (int k0 = 0; k0 < 8192; k0 += 64) {
        for (int i = tid; i < 512; i += 256) {
            int r = i / 16, q = i % 16;
            float4 av = *(const float4*)&A[(long)(ob + r) * 8192 + k0 + q * 4];
            As[r][q * 4 + 0] = av.x; As[r][q * 4 + 1] = av.y;
            As[r][q * 4 + 2] = av.z; As[r][q * 4 + 3] = av.w;
            float4 wv = *(const float4*)&W[(long)(oo + r) * 8192 + k0 + q * 4];
            Ws[r][q * 4 + 0] = wv.x; Ws[r][q * 4 + 1] = wv.y;
            Ws[r][q * 4 + 2] = wv.z; Ws[r][q * 4 + 3] = wv.w;
        }
        __syncthreads();
#pragma unroll
        for (int kk = 0; kk < 64; kk++) {
            float a0 = As[ty * 2][kk], a1 = As[ty * 2 + 1][kk];
            float w0 = Ws[tx * 2][kk], w1 = Ws[tx * 2 + 1][kk];
            acc00 = fmaf(a0, w0, acc00); acc01 = fmaf(a0, w1, acc01);
            acc10 = fmaf(a1, w0, acc10); acc11 = fmaf(a1, w1, acc11);
        }
        __syncthreads();
    }
    float b0 = bias[oo + tx * 2], b1 = bias[oo + tx * 2 + 1];
    float v;
    v = acc00 + b0; out[(long)(ob + ty * 2) * 1024 + oo + tx * 2] = v > 0.f ? v : 0.f;
    v = acc01 + b1; out[(long)(ob + ty * 2) * 1024 + oo + tx * 2 + 1] = v > 0.f ? v : 0.f;
    v = acc10 + b0; out[(long)(ob + ty * 2 + 1) * 1024 + oo + tx * 2] = v > 0.f ? v : 0.f;
    v = acc11 + b1; out[(long)(ob + ty * 2 + 1) * 1024 + oo + tx * 2 + 1] = v > 0.f ? v : 0.f;
}

__global__ void fc2_k(const float* __restrict__ A, const float* __restrict__ W,
                      const float* __restrict__ b2, float* __restrict__ out) {
    int bb = blockIdx.x;
    int tid = threadIdx.x;
    float acc[10];
#pragma unroll
    for (int o = 0; o < 10; o++) acc[o] = 0.f;
    const float* arow = A + (long)bb * 1024;
    for (int k = tid; k < 1024; k += 256) {
        float a = arow[k];
#pragma unroll
        for (int o = 0; o < 10; o++) acc[o] = fmaf(a, W[o * 1024 + k], acc[o]);
    }
#pragma unroll
    for (int o = 0; o < 10; o++)
        for (int off = 32; off > 0; off >>= 1) acc[o] += __shfl_down(acc[o], off);
    __shared__ float red[10][4];
    int wid = tid >> 6, lane = tid & 63;
    if (lane == 0) {
#pragma unroll
        for (int o = 0; o < 10; o++) red[o][wid] = acc[o];
    }
    __syncthreads();
    if (tid < 10)
        out[bb * 10 + tid] = red[tid][0] + red[tid][1] + red[tid][2] + red[tid][3] + b2[tid];
}

// ---------------------------------------------------------------------------
extern "C" void kernel_launch(void* const* d_in, const int* in_sizes, int n_in,
                              void* d_out, int out_size, void* d_ws, size_t ws_size,
                              hipStream_t stream) {
    const float* x  = (const float*)d_in[0];
    const float* a1 = (const float*)d_in[1];  const float* b1 = (const float*)d_in[2];  const float* c1 = (const float*)d_in[3];
    const float* a2 = (const float*)d_in[4];  const float* b2 = (const float*)d_in[5];  const float* c2 = (const float*)d_in[6];
    const float* a3 = (const float*)d_in[7];  const float* b3 = (const float*)d_in[8];  const float* c3 = (const float*)d_in[9];
    const float* a4 = (const float*)d_in[10]; const float* b4 = (const float*)d_in[11]; const float* c4 = (const float*)d_in[12];
    const float* a5 = (const float*)d_in[13]; const float* b5 = (const float*)d_in[14]; const float* c5 = (const float*)d_in[15];
    const float* a6 = (const float*)d_in[16]; const float* b6 = (const float*)d_in[17]; const float* c6 = (const float*)d_in[18];
    const float* g3 = (const float*)d_in[19]; const float* be3 = (const float*)d_in[20];
    const float* g6 = (const float*)d_in[21]; const float* be6 = (const float*)d_in[22];
    const float* fc1w = (const float*)d_in[23]; const float* fc1b = (const float*)d_in[24];
    const float* fc2w = (const float*)d_in[25]; const float* fc2b = (const float*)d_in[26];
    const float* eps3 = (const float*)d_in[27]; const float* eps6 = (const float*)d_in[28];
    (void)in_sizes; (void)n_in; (void)out_size; (void)ws_size;

    float* w = (float*)d_ws;
    size_t off = 0;
    auto alloc = [&](size_t n) { float* p = w + off; off += n; return p; };
    unsigned short* pk2 = (unsigned short*)alloc(147456);
    unsigned short* pk3 = (unsigned short*)alloc(294912);
    unsigned short* pk4 = (unsigned short*)alloc(589824);
    unsigned short* pk5 = (unsigned short*)alloc(1179648);
    unsigned short* pk6 = (unsigned short*)alloc(2359296);
    float* wa1 = alloc(3456); float* wb1 = alloc(3456);
    float* ss2 = alloc(1152); float* ss3 = alloc(2304);
    float* ss5 = alloc(4608); float* ss6 = alloc(4608);
    float* og2 = alloc(32768); float* og3 = alloc(65536);
    float* og5 = alloc(32768); float* og6 = alloc(8192);
    float* st3 = alloc(512);  float* st6 = alloc(1024);
    float* A  = alloc(16777216);  // ex1 (bf16) -> h3 (f32)
    float* Bb = alloc(4194304);   // ex2 (bf16) -> fco (f32)
    float* Cc = alloc(8388608);   // h3t (bf16) -> h6 (f32)
    float* Dd = alloc(2097152);   // ex4 (bf16)
    float* Ee = alloc(4194304);   // ex5 (bf16)

    unsigned short* ex1 = (unsigned short*)A;
    float*          h3  = A;
    unsigned short* ex2 = (unsigned short*)Bb;
    float*          fco = Bb;
    unsigned short* h3t = (unsigned short*)Cc;
    float*          h6  = Cc;
    unsigned short* ex4 = (unsigned short*)Dd;
    unsigned short* ex5 = (unsigned short*)Ee;

    // ---- prep ----
    prep_w<<<14, 256, 0, stream>>>(a1, b1, wa1, wb1, 3456);
    prep_pack<<<72,  256, 0, stream>>>(a2, b2, pk2, 128, 128, 1, 18432);
    prep_pack<<<144, 256, 0, stream>>>(a3, b3, pk3, 128, 256, 1, 36864);
    prep_pack<<<288, 256, 0, stream>>>(a4, b4, pk4, 256, 256, 0, 73728);
    prep_pack<<<576, 256, 0, stream>>>(a5, b5, pk5, 256, 512, 1, 147456);
    prep_pack<<<1152,256, 0, stream>>>(a6, b6, pk6, 512, 512, 1, 294912);
    prep_s<<<128, 64, 0, stream>>>(a2, ss2, 128);
    prep_s<<<256, 64, 0, stream>>>(a3, ss3, 128);
    prep_s<<<512, 64, 0, stream>>>(a5, ss5, 256);
    prep_s<<<512, 64, 0, stream>>>(a6, ss6, 512);
    prep_ones<<<128, 256, 0, stream>>>(ss2, og2, 128, 16, 16, 32, 32, 2, 32768);
    prep_ones<<<256, 256, 0, stream>>>(ss3, og3, 256, 16, 16, 16, 16, 1, 65536);
    prep_ones<<<128, 256, 0, stream>>>(ss5, og5, 512, 8, 8, 8, 8, 1, 32768);
    prep_ones<<<32,  256, 0, stream>>>(ss6, og6, 512, 4, 4, 8, 8, 2, 8192);

    // ---- network ----
    conv1_k<<<4096, 256, 0, stream>>>(x, wa1, wb1, c1, ex1);
    // L2: [256,32,32,128] -> [256,16,16,128]
    conv_mfma<128,32,32,128,16,16,2, 8,1,128,1><<<512, 256, 0, stream>>>(ex1, pk2, c2, og2, nullptr, ex2);
    // L3: -> h3 [256,256,16,16] NCHW f32 (sampled)
    conv_mfma<128,16,16,256,16,16,1, 8,1,128,2><<<1024, 256, 0, stream>>>(ex2, pk3, c3, og3, eps3, h3);
    // BN3 + relu + transpose to NHWC bf16
    hipMemsetAsync(st3, 0, 512 * sizeof(float), stream);
    bn_stats<<<dim3(256, 8), 256, 0, stream>>>(h3, st3, 256, 256, 32);
    bn_apply_t<<<4096, 256, 0, stream>>>(h3, st3, g3, be3, h3t);
    // L4: [256,16,16,256] -> [256,8,8,256]
    conv_mfma<256,16,16,256, 8, 8,2, 8,2,128,0><<<256, 256, 0, stream>>>(h3t, pk4, c4, nullptr, nullptr, ex4);
    // L5: -> [256,8,8,512]
    conv_mfma<256, 8, 8,512, 8, 8,1, 8,2,128,1><<<512, 256, 0, stream>>>(ex4, pk5, c5, og5, nullptr, ex5);
    // L6: -> h6 [256,512,4,4] NCHW f32 (sampled)
    conv_mfma<512, 8, 8,512, 4, 4,2, 4,4, 64,2><<<256, 256, 0, stream>>>(ex5, pk6, c6, og6, eps6, h6);
    // BN6 + relu (in place)
    hipMemsetAsync(st6, 0, 1024 * sizeof(float), stream);
    bn_stats<<<dim3(512, 8), 256, 0, stream>>>(h6, st6, 512, 16, 32);
    bn_apply<<<2048, 256, 0, stream>>>(h6, st6, g6, be6, 512, 16, (long)256 * 512 * 16, 1.f / 4096.f);
    // FC
    fc1_k<<<dim3(32, 8), 256, 0, stream>>>(h6, fc1w, fc1b, fco);
    fc2_k<<<256, 256, 0, stream>>>(fco, fc2w, fc2b, (float*)d_out);
}

// Round 4
// 998.201 us; speedup vs baseline: 5.6844x; 1.2745x over previous
//
#include <hip/hip_runtime.h>
#include <hip/hip_bf16.h>
#include <math.h>

#define EPSV 1e-10f
#define BNEPS 1e-5f
#define INV_SQRT2 0.70710678118654752440f

typedef __attribute__((ext_vector_type(8))) short short8;
typedef __attribute__((ext_vector_type(4))) float f32x4;

__device__ __forceinline__ float bf2f(unsigned short u) {
    union { unsigned int i; float f; } c; c.i = ((unsigned int)u) << 16; return c.f;
}
__device__ __forceinline__ unsigned short f2bf(float f) {
    unsigned int u = __float_as_uint(f);
    return (unsigned short)((u + 0x7FFFu + ((u >> 16) & 1u)) >> 16);
}

// ---------------------------------------------------------------------------
// L1 weight prep (fp32, OIHW kept): e_w and var_w
// ---------------------------------------------------------------------------
__global__ void prep_w(const float* __restrict__ a, const float* __restrict__ b,
                       float* __restrict__ WA, float* __restrict__ WB, int n) {
    for (int i = blockIdx.x * blockDim.x + threadIdx.x; i < n; i += gridDim.x * blockDim.x) {
        float p0 = 1.f / (1.f + expf(-a[i]));
        float sb = 1.f / (1.f + expf(-b[i]));
        float p1 = (1.f - p0) * sb;
        float ew = 2.f * p1 - (1.f - p0);
        float ew2 = 1.f - p0;
        WA[i] = ew;
        WB[i] = ew2 - ew * ew;
    }
}

// ---------------------------------------------------------------------------
// Pack ternary-stat weights into MFMA A-fragment order (bf16).
// index: ((((cv*9+pos)*NCH + ch)*MFg + mf)*64 + lane)*8 + j
//   co = mf*16 + (lane&15), ci = ch*32 + (lane>>4)*8 + j
// cv=0 -> e_w ; cv=1 -> (ver2 ? e_w^2 : var_w)
// ---------------------------------------------------------------------------
__global__ void prep_pack(const float* __restrict__ a, const float* __restrict__ b,
                          unsigned short* __restrict__ pk, int Ci, int Co, int ver2, int total) {
    int idx = blockIdx.x * 256 + threadIdx.x;
    if (idx >= total) return;
    int lane = idx & 63;
    int MFg = Co >> 4, NCH = Ci >> 5;
    int mfch = idx >> 6;
    int mf = mfch % MFg;
    int chpos = mfch / MFg;
    int ch = chpos % NCH;
    int pos = chpos / NCH;
    int co = mf * 16 + (lane & 15);
    int cib = ch * 32 + (lane >> 4) * 8;
    unsigned int wa[4], wb[4];
#pragma unroll
    for (int j = 0; j < 8; j++) {
        long s = ((long)co * Ci + cib + j) * 9 + pos;
        float p0 = 1.f / (1.f + expf(-a[s]));
        float sb = 1.f / (1.f + expf(-b[s]));
        float p1 = (1.f - p0) * sb;
        float ew = 2.f * p1 - (1.f - p0);
        float ew2 = 1.f - p0;
        unsigned int ha = f2bf(ew);
        unsigned int hb = f2bf(ver2 ? ew * ew : ew2 - ew * ew);
        if (j & 1) { wa[j >> 1] |= ha << 16; wb[j >> 1] |= hb << 16; }
        else       { wa[j >> 1] = ha;        wb[j >> 1] = hb; }
    }
    long b0 = (((long)(0 * 9 + pos) * NCH + ch) * MFg + mf) * 64 + lane;
    long b1 = (((long)(1 * 9 + pos) * NCH + ch) * MFg + mf) * 64 + lane;
    uint4 va; va.x = wa[0]; va.y = wa[1]; va.z = wa[2]; va.w = wa[3];
    uint4 vb; vb.x = wb[0]; vb.y = wb[1]; vb.z = wb[2]; vb.w = wb[3];
    *(uint4*)(pk + b0 * 8) = va;
    *(uint4*)(pk + b1 * 8) = vb;
}

// ssum[co][k] = sum_ci sigmoid(-alpha)   (= sum_ci E[w^2])
__global__ void prep_s(const float* __restrict__ alpha, float* __restrict__ s, int Ci) {
    int co = blockIdx.x;
    int lane = threadIdx.x; // 64
    float acc[9];
#pragma unroll
    for (int k = 0; k < 9; k++) acc[k] = 0.f;
    for (int ci = lane; ci < Ci; ci += 64) {
        const float* p = alpha + ((long)co * Ci + ci) * 9;
#pragma unroll
        for (int k = 0; k < 9; k++) acc[k] += 1.f / (1.f + expf(p[k]));
    }
#pragma unroll
    for (int k = 0; k < 9; k++) {
        for (int off = 32; off > 0; off >>= 1) acc[k] += __shfl_down(acc[k], off);
    }
    if (lane == 0) {
#pragma unroll
        for (int k = 0; k < 9; k++) s[co * 9 + k] = acc[k];
    }
}

// ones_grid[co][y][x] = sum over valid (ky,kx) of ssum[co][ky*3+kx]
__global__ void prep_ones(const float* __restrict__ ssum, float* __restrict__ og,
                          int Co, int Hout, int Wout, int Hin, int Win, int stride, int total) {
    int idx = blockIdx.x * 256 + threadIdx.x;
    if (idx >= total) return;
    int x = idx % Wout, y = (idx / Wout) % Hout, co = idx / (Wout * Hout);
    float s = 0.f;
    for (int ky = 0; ky < 3; ky++) {
        int yi = stride * y - 1 + ky;
        if (yi < 0 || yi >= Hin) continue;
        for (int kx = 0; kx < 3; kx++) {
            int xi = stride * x - 1 + kx;
            if (xi < 0 || xi >= Win) continue;
            s += ssum[co * 9 + ky * 3 + kx];
        }
    }
    og[idx] = s;
}

// ---------------------------------------------------------------------------
// FC1 weight pack: fp32 [1024][8192] -> bf16 A-fragment order
// idx = ((kt*64 + mf)*64 + lane)*8 ; o = mf*16+(lane&15), k = kt*32+(lane>>4)*8+j
// ---------------------------------------------------------------------------
__global__ void prep_fc1(const float* __restrict__ W, unsigned short* __restrict__ pk) {
    int idx = blockIdx.x * 256 + threadIdx.x;      // 1048576 total
    int lane = idx & 63;
    int mf = (idx >> 6) & 63;
    int kt = idx >> 12;
    int o = mf * 16 + (lane & 15);
    long k = (long)kt * 32 + (lane >> 4) * 8;
    const float* src = W + (long)o * 8192 + k;
    float4 f0 = *(const float4*)src;
    float4 f1 = *(const float4*)(src + 4);
    uint4 v;
    v.x = (unsigned)f2bf(f0.x) | ((unsigned)f2bf(f0.y) << 16);
    v.y = (unsigned)f2bf(f0.z) | ((unsigned)f2bf(f0.w) << 16);
    v.z = (unsigned)f2bf(f1.x) | ((unsigned)f2bf(f1.y) << 16);
    v.w = (unsigned)f2bf(f1.z) | ((unsigned)f2bf(f1.w) << 16);
    *(uint4*)(pk + (long)idx * 8) = v;
}

// ---------------------------------------------------------------------------
// L1: fp32 vector conv (Ci=3) -> erf -> NHWC bf16.
// ---------------------------------------------------------------------------
__global__ __launch_bounds__(256) void conv1_k(const float* __restrict__ x,
        const float* __restrict__ wa, const float* __restrict__ wb,
        const float* __restrict__ bias, unsigned short* __restrict__ out) {
    __shared__ float win[3 * 4 * 34];          // [ci][4 rows][34]
    __shared__ float wl[128 * 56];             // [co][28][(wa,wb)] interleaved
    int b = blockIdx.x >> 4;
    int y0 = (blockIdx.x & 15) * 2;
    int tid = threadIdx.x;
    for (int i = tid; i < 408; i += 256) {
        int ci = i / 136, r = (i % 136) / 34, px = i % 34;
        int yy = y0 - 1 + r, xx = px - 1;
        float v = 0.f;
        if (yy >= 0 && yy < 32 && xx >= 0 && xx < 32)
            v = x[((b * 3 + ci) * 32 + yy) * 32 + xx];
        win[i] = v;
    }
    for (int i = tid; i < 128 * 56; i += 256) {
        int co = i / 56, q = i % 56, j = q >> 1;
        float v = 0.f;
        if (j < 27) v = (q & 1) ? wb[co * 27 + j] : wa[co * 27 + j];
        wl[i] = v;
    }
    __syncthreads();
    int xo = tid & 31;
    int cog = tid >> 5;
    float iv[2][28], sq[2][28];
#pragma unroll
    for (int r = 0; r < 2; r++) {
#pragma unroll
        for (int ci = 0; ci < 3; ci++)
#pragma unroll
        for (int ky = 0; ky < 3; ky++)
#pragma unroll
        for (int kx = 0; kx < 3; kx++) {
            float v = win[(ci * 4 + r + ky) * 34 + xo + kx];
            iv[r][ci * 9 + ky * 3 + kx] = v;
            sq[r][ci * 9 + ky * 3 + kx] = v * v;
        }
        iv[r][27] = 0.f; sq[r][27] = 0.f;
    }
    unsigned int pk[2][8];
#pragma unroll
    for (int k = 0; k < 16; k++) {
        int co = cog * 16 + k;
        const float4* wp = (const float4*)&wl[co * 56];
        float bs = bias[co];
        float m0 = bs, v0 = 0.f, m1 = bs, v1 = 0.f;
#pragma unroll
        for (int q = 0; q < 14; q++) {
            float4 w4 = wp[q];
            m0 = fmaf(iv[0][2 * q], w4.x, m0);     v0 = fmaf(sq[0][2 * q], w4.y, v0);
            m0 = fmaf(iv[0][2 * q + 1], w4.z, m0); v0 = fmaf(sq[0][2 * q + 1], w4.w, v0);
            m1 = fmaf(iv[1][2 * q], w4.x, m1);     v1 = fmaf(sq[1][2 * q], w4.y, v1);
            m1 = fmaf(iv[1][2 * q + 1], w4.z, m1); v1 = fmaf(sq[1][2 * q + 1], w4.w, v1);
        }
        unsigned int h0 = f2bf(erff(m0 * rsqrtf(v0 + EPSV) * INV_SQRT2));
        unsigned int h1 = f2bf(erff(m1 * rsqrtf(v1 + EPSV) * INV_SQRT2));
        if (k & 1) { pk[0][k >> 1] |= h0 << 16; pk[1][k >> 1] |= h1 << 16; }
        else       { pk[0][k >> 1] = h0;        pk[1][k >> 1] = h1; }
    }
#pragma unroll
    for (int r = 0; r < 2; r++) {
        long oa = (((long)b * 32 + y0 + r) * 32 + xo) * 128 + cog * 16;
        uint4 u0; u0.x = pk[r][0]; u0.y = pk[r][1]; u0.z = pk[r][2]; u0.w = pk[r][3];
        uint4 u1; u1.x = pk[r][4]; u1.y = pk[r][5]; u1.z = pk[r][6]; u1.w = pk[r][7];
        *(uint4*)(out + oa) = u0;
        *(uint4*)(out + oa + 8) = u1;
    }
}

// ---------------------------------------------------------------------------
// MFMA implicit-GEMM fused LRnet conv. NHWC bf16 input.
// MODE 0: lrconv  -> erf -> NHWC bf16      (v = convB)
// MODE 1: ver2    -> erf -> NHWC bf16      (v = ones - convB)
// MODE 2: ver2 + sample -> NCHW fp32       (out = m + sqrt(v+eps)*epsb)
// ---------------------------------------------------------------------------
template<int Ci, int Hin, int Win, int Co, int Hout, int Wout, int STRIDE,
         int ROWS, int IPB, int NTILE, int MODE>
__global__ __launch_bounds__(256, 2) void conv_mfma(
    const unsigned short* __restrict__ in,
    const unsigned short* __restrict__ wpk,
    const float* __restrict__ bias,
    const float* __restrict__ ones_g,
    const float* __restrict__ epsb,
    void* __restrict__ outp)
{
    constexpr int MTILE = 128;
    constexpr int PROWS = STRIDE * (ROWS - 1) + 3;
    constexpr int PW = Win + 2;
    constexpr int POS = IPB * PROWS * PW;
    constexpr int NCH = Ci / 32;
    constexpr int MFg = Co / 16;
    constexpr int NF = NTILE / 16;
    constexpr int WMF = 4;
    constexpr int WNF = NF / 2;
    constexpr int CT = Co / MTILE;
    constexpr int RG = Hout / ROWS;
    constexpr int LINE = 80;               // bytes per position per array
    constexpr int XS = POS * LINE;         // x^2 array offset
    constexpr int TSTR = MTILE + 8;
    constexpr int STAGE_B = 2 * POS * LINE;
    constexpr int TR_B = (MODE == 2) ? 0 : NTILE * TSTR * 2;
    constexpr int LDS_B = STAGE_B > TR_B ? STAGE_B : TR_B;
    __shared__ char lds[LDS_B];

    const int tid = threadIdx.x;
    const int lane = tid & 63;
    const int wv = tid >> 6;
    const int wm = wv & 1, wn = wv >> 1;
    const int g = lane >> 4, ln = lane & 15;

    const int bid = blockIdx.x;
    const int ct = bid % CT;
    const int nt = bid / CT;
    const int b0 = (nt / RG) * IPB;
    const int y0 = (nt % RG) * ROWS;

    int pbase[WNF];
#pragma unroll
    for (int nf = 0; nf < WNF; nf++) {
        int n = (wn * WNF + nf) * 16 + ln;
        int img = n / (ROWS * Wout);
        int rem = n % (ROWS * Wout);
        int yr = rem / Wout, xo = rem % Wout;
        pbase[nf] = (img * PROWS + STRIDE * yr) * PW + STRIDE * xo;
    }

    f32x4 accA[WMF][WNF], accB[WMF][WNF];
#pragma unroll
    for (int mf = 0; mf < WMF; mf++)
#pragma unroll
    for (int nf = 0; nf < WNF; nf++) {
        accA[mf][nf] = (f32x4){0.f, 0.f, 0.f, 0.f};
        accB[mf][nf] = (f32x4){0.f, 0.f, 0.f, 0.f};
    }

    const unsigned short* wbase = wpk + ((long)(ct * 8 + wm * WMF) * 64 + lane) * 8;

    for (int ch = 0; ch < NCH; ch++) {
        // ---- stage x, x^2 (bf16) into LDS ----
        for (int i = tid; i < POS * 4; i += 256) {
            int p = i >> 2, c = i & 3;
            int img = p / (PROWS * PW);
            int r = p % (PROWS * PW);
            int prow = r / PW, px = r % PW;
            int yin = STRIDE * y0 - 1 + prow;
            int xin = px - 1;
            uint4 v; v.x = 0; v.y = 0; v.z = 0; v.w = 0;
            if (yin >= 0 && yin < Hin && xin >= 0 && xin < Win) {
                long a = (((long)(b0 + img) * Hin + yin) * Win + xin) * Ci + ch * 32 + c * 8;
                v = *(const uint4*)(in + a);
            }
            *(uint4*)(lds + p * LINE + c * 16) = v;
            uint4 s;
            unsigned int* vp = (unsigned int*)&v;
            unsigned int* sp = (unsigned int*)&s;
#pragma unroll
            for (int e = 0; e < 4; e++) {
                float lo = bf2f((unsigned short)(vp[e] & 0xffffu));
                float hi = bf2f((unsigned short)(vp[e] >> 16));
                sp[e] = (unsigned int)f2bf(lo * lo) | (((unsigned int)f2bf(hi * hi)) << 16);
            }
            *(uint4*)(lds + XS + p * LINE + c * 16) = s;
        }
        __syncthreads();
        // ---- 9 kernel positions ----
#pragma unroll 3
        for (int pos = 0; pos < 9; pos++) {
            const int ky = pos / 3, kx = pos % 3;
            short8 af[2][WMF];
#pragma unroll
            for (int cv = 0; cv < 2; cv++)
#pragma unroll
            for (int mf = 0; mf < WMF; mf++)
                af[cv][mf] = *(const short8*)(wbase +
                    ((long)(((cv * 9 + pos) * NCH + ch) * MFg + mf)) * 512);
            short8 bx[WNF], bq[WNF];
#pragma unroll
            for (int nf = 0; nf < WNF; nf++) {
                int po = (pbase[nf] + ky * PW + kx) * LINE + g * 16;
                bx[nf] = *(const short8*)(lds + po);
                bq[nf] = *(const short8*)(lds + XS + po);
            }
#pragma unroll
            for (int mf = 0; mf < WMF; mf++)
#pragma unroll
            for (int nf = 0; nf < WNF; nf++) {
                accA[mf][nf] = __builtin_amdgcn_mfma_f32_16x16x32_bf16(af[0][mf], bx[nf], accA[mf][nf], 0, 0, 0);
                accB[mf][nf] = __builtin_amdgcn_mfma_f32_16x16x32_bf16(af[1][mf], bq[nf], accB[mf][nf], 0, 0, 0);
            }
        }
        __syncthreads();
    }

    // ---- epilogue ----
    if constexpr (MODE == 2) {
        float* out = (float*)outp;
#pragma unroll
        for (int mf = 0; mf < WMF; mf++) {
            int co = ct * MTILE + (wm * WMF + mf) * 16 + g * 4;
#pragma unroll
            for (int nf = 0; nf < WNF; nf++) {
                int n = (wn * WNF + nf) * 16 + ln;
                int img = n / (ROWS * Wout), rem = n % (ROWS * Wout);
                int y = y0 + rem / Wout, x = rem % Wout;
                int b = b0 + img;
#pragma unroll
                for (int r = 0; r < 4; r++) {
                    int c = co + r;
                    float m = accA[mf][nf][r] + bias[c];
                    float v = ones_g[(c * Hout + y) * Wout + x] - accB[mf][nf][r];
                    long oi = (((long)b * Co + c) * Hout + y) * Wout + x;
                    out[oi] = m + sqrtf(v + EPSV) * epsb[oi];
                }
            }
        }
    } else {
        unsigned short* out = (unsigned short*)outp;
#pragma unroll
        for (int mf = 0; mf < WMF; mf++) {
            int cob = (wm * WMF + mf) * 16 + g * 4;
            int cg = ct * MTILE + cob;
#pragma unroll
            for (int nf = 0; nf < WNF; nf++) {
                int n = (wn * WNF + nf) * 16 + ln;
                int img = n / (ROWS * Wout), rem = n % (ROWS * Wout);
                int y = y0 + rem / Wout, x = rem % Wout;
                unsigned int pk2[2];
#pragma unroll
                for (int r = 0; r < 4; r++) {
                    int c = cg + r;
                    float m = accA[mf][nf][r] + bias[c];
                    float v;
                    if constexpr (MODE == 1)
                        v = ones_g[(c * Hout + y) * Wout + x] - accB[mf][nf][r];
                    else
                        v = accB[mf][nf][r];
                    unsigned int hv = f2bf(erff(m * rsqrtf(v + EPSV) * INV_SQRT2));
                    if (r & 1) pk2[r >> 1] |= hv << 16; else pk2[r >> 1] = hv;
                }
                *(unsigned int*)(lds + (n * TSTR + cob) * 2) = pk2[0];
                *(unsigned int*)(lds + (n * TSTR + cob) * 2 + 4) = pk2[1];
            }
        }
        __syncthreads();
        for (int i = tid; i < NTILE * (MTILE / 8); i += 256) {
            int n = i / (MTILE / 8);
            int c8 = (i % (MTILE / 8)) * 8;
            int img = n / (ROWS * Wout), rem = n % (ROWS * Wout);
            int y = y0 + rem / Wout, x = rem % Wout;
            int b = b0 + img;
            uint4 val = *(const uint4*)(lds + (n * TSTR + c8) * 2);
            long oa = (((long)b * Hout + y) * Wout + x) * Co + ct * MTILE + c8;
            *(uint4*)(out + oa) = val;
        }
    }
}

// ---------------------------------------------------------------------------
// BatchNorm
// ---------------------------------------------------------------------------
__global__ void bn_stats(const float* __restrict__ h, float* __restrict__ st,
                         int C, int HW, int Bchunk) {
    int c = blockIdx.x;
    int chunk = blockIdx.y;
    int tid = threadIdx.x;
    float s = 0.f, s2 = 0.f;
    int total = Bchunk * HW;
    int bbase = chunk * Bchunk;
    for (int j = tid; j < total; j += 256) {
        int b = bbase + j / HW;
        int i = j % HW;
        float v = h[((long)b * C + c) * HW + i];
        s += v; s2 += v * v;
    }
    for (int off = 32; off > 0; off >>= 1) {
        s += __shfl_down(s, off);
        s2 += __shfl_down(s2, off);
    }
    __shared__ float red[8];
    int wid = tid >> 6, lane = tid & 63;
    if (lane == 0) { red[wid] = s; red[4 + wid] = s2; }
    __syncthreads();
    if (tid == 0) {
        atomicAdd(&st[c], red[0] + red[1] + red[2] + red[3]);
        atomicAdd(&st[C + c], red[4] + red[5] + red[6] + red[7]);
    }
}

// h6 in-place NCHW fp32 BN+relu, plus bf16 copy for FC1
__global__ void bn_apply(float* __restrict__ h, const float* __restrict__ st,
                         const float* __restrict__ gamma, const float* __restrict__ beta,
                         unsigned short* __restrict__ hb,
                         int C, int HW, long N, float invN) {
    for (long idx = (long)blockIdx.x * blockDim.x + threadIdx.x; idx < N;
         idx += (long)gridDim.x * blockDim.x) {
        int c = (int)((idx / HW) % C);
        float mean = st[c] * invN;
        float var = st[C + c] * invN - mean * mean;
        float v = gamma[c] * (h[idx] - mean) * rsqrtf(var + BNEPS) + beta[c];
        v = v > 0.f ? v : 0.f;
        h[idx] = v;
        hb[idx] = f2bf(v);
    }
}

// h3: NCHW fp32 -> BN+relu -> NHWC bf16 (block per (b,y), C=256, W=16)
__global__ __launch_bounds__(256) void bn_apply_t(const float* __restrict__ h,
        const float* __restrict__ st, const float* __restrict__ gamma,
        const float* __restrict__ beta, unsigned short* __restrict__ out) {
    __shared__ float t[256 * 17];
    int b = blockIdx.x >> 4, y = blockIdx.x & 15;
    int tid = threadIdx.x;
    const float invN = 1.f / 65536.f;
    for (int i = tid; i < 4096; i += 256) {
        int c = i >> 4, xx = i & 15;
        float mean = st[c] * invN;
        float var = st[256 + c] * invN - mean * mean;
        float v = h[(((long)b * 256 + c) * 16 + y) * 16 + xx];
        v = gamma[c] * (v - mean) * rsqrtf(var + BNEPS) + beta[c];
        t[c * 17 + xx] = v > 0.f ? v : 0.f;
    }
    __syncthreads();
    for (int i = tid; i < 4096; i += 256) {
        int xx = i >> 8, c = i & 255;
        out[(((long)b * 16 + y) * 16 + xx) * 256 + c] = f2bf(t[c * 17 + xx]);
    }
}

// ---------------------------------------------------------------------------
// FC1 bf16 MFMA split-K: pbuf[s][256][1024] partials
// grid (8 o-tiles, 4 b-tiles, 8 K-splits); block 256 = 4 waves
// ---------------------------------------------------------------------------
__global__ __launch_bounds__(256) void fc1_mfma(const unsigned short* __restrict__ Ab,
                                                const unsigned short* __restrict__ Wp,
                                                float* __restrict__ pbuf) {
    __shared__ char lds[2 * 64 * 80];
    const int tid = threadIdx.x;
    const int lane = tid & 63;
    const int wv = tid >> 6;
    const int g = lane >> 4, ln = lane & 15;
    const int ot = blockIdx.x, bt = blockIdx.y, s = blockIdx.z;
    const int b0 = bt * 64;
    const int k0g = s * 1024;

    f32x4 acc[2][4];
#pragma unroll
    for (int c = 0; c < 2; c++)
#pragma unroll
    for (int nf = 0; nf < 4; nf++) acc[c][nf] = (f32x4){0.f, 0.f, 0.f, 0.f};

    for (int k0 = 0; k0 < 1024; k0 += 64) {
        __syncthreads();
        for (int i = tid; i < 512; i += 256) {
            int row = i >> 3, kk = (i >> 2) & 1, seg = i & 3;
            uint4 v = *(const uint4*)(Ab + ((long)(b0 + row) * 8192 + k0g + k0 + kk * 32 + seg * 8));
            *(uint4*)(lds + (kk * 64 + row) * 80 + seg * 16) = v;
        }
        __syncthreads();
#pragma unroll
        for (int kk = 0; kk < 2; kk++) {
            int kt = (k0g + k0) / 32 + kk;
            short8 af[2];
#pragma unroll
            for (int c = 0; c < 2; c++) {
                int mf = ot * 8 + wv * 2 + c;
                af[c] = *(const short8*)(Wp + (((long)kt * 64 + mf) * 64 + lane) * 8);
            }
            short8 bf[4];
#pragma unroll
            for (int nf = 0; nf < 4; nf++)
                bf[nf] = *(const short8*)(lds + (kk * 64 + nf * 16 + ln) * 80 + g * 16);
#pragma unroll
            for (int c = 0; c < 2; c++)
#pragma unroll
            for (int nf = 0; nf < 4; nf++)
                acc[c][nf] = __builtin_amdgcn_mfma_f32_16x16x32_bf16(af[c], bf[nf], acc[c][nf], 0, 0, 0);
        }
    }
#pragma unroll
    for (int c = 0; c < 2; c++) {
        int o = ot * 128 + (wv * 2 + c) * 16 + g * 4;
#pragma unroll
        for (int nf = 0; nf < 4; nf++) {
            int b = b0 + nf * 16 + ln;
            *(f32x4*)(pbuf + ((long)s * 256 + b) * 1024 + o) = acc[c][nf];
        }
    }
}

__global__ void fc1_reduce(const float* __restrict__ pbuf, const float* __restrict__ bias,
                           float* __restrict__ out) {
    int idx = blockIdx.x * 256 + threadIdx.x;   // 262144
    float s = 0.f;
#pragma unroll
    for (int j = 0; j < 8; j++) s += pbuf[(long)j * 262144 + idx];
    s += bias[idx & 1023];
    out[idx] = s > 0.f ? s : 0.f;
}

__global__ void fc2_k(const float* __restrict__ A, const float* __restrict__ W,
                      const float* __restrict__ b2, float* __restrict__ out) {
    int bb = blockIdx.x;
    int tid = threadIdx.x;
    float acc[10];
#pragma unroll
    for (int o = 0; o < 10; o++) acc[o] = 0.f;
    const float* arow = A + (long)bb * 1024;
    for (int k = tid; k < 1024; k += 256) {
        float a = arow[k];
#pragma unroll
        for (int o = 0; o < 10; o++) acc[o] = fmaf(a, W[o * 1024 + k], acc[o]);
    }
#pragma unroll
    for (int o = 0; o < 10; o++)
        for (int off = 32; off > 0; off >>= 1) acc[o] += __shfl_down(acc[o], off);
    __shared__ float red[10][4];
    int wid = tid >> 6, lane = tid & 63;
    if (lane == 0) {
#pragma unroll
        for (int o = 0; o < 10; o++) red[o][wid] = acc[o];
    }
    __syncthreads();
    if (tid < 10)
        out[bb * 10 + tid] = red[tid][0] + red[tid][1] + red[tid][2] + red[tid][3] + b2[tid];
}

// ---------------------------------------------------------------------------
extern "C" void kernel_launch(void* const* d_in, const int* in_sizes, int n_in,
                              void* d_out, int out_size, void* d_ws, size_t ws_size,
                              hipStream_t stream) {
    const float* x  = (const float*)d_in[0];
    const float* a1 = (const float*)d_in[1];  const float* b1 = (const float*)d_in[2];  const float* c1 = (const float*)d_in[3];
    const float* a2 = (const float*)d_in[4];  const float* b2 = (const float*)d_in[5];  const float* c2 = (const float*)d_in[6];
    const float* a3 = (const float*)d_in[7];  const float* b3 = (const float*)d_in[8];  const float* c3 = (const float*)d_in[9];
    const float* a4 = (const float*)d_in[10]; const float* b4 = (const float*)d_in[11]; const float* c4 = (const float*)d_in[12];
    const float* a5 = (const float*)d_in[13]; const float* b5 = (const float*)d_in[14]; const float* c5 = (const float*)d_in[15];
    const float* a6 = (const float*)d_in[16]; const float* b6 = (const float*)d_in[17]; const float* c6 = (const float*)d_in[18];
    const float* g3 = (const float*)d_in[19]; const float* be3 = (const float*)d_in[20];
    const float* g6 = (const float*)d_in[21]; const float* be6 = (const float*)d_in[22];
    const float* fc1w = (const float*)d_in[23]; const float* fc1b = (const float*)d_in[24];
    const float* fc2w = (const float*)d_in[25]; const float* fc2b = (const float*)d_in[26];
    const float* eps3 = (const float*)d_in[27]; const float* eps6 = (const float*)d_in[28];
    (void)in_sizes; (void)n_in; (void)out_size; (void)ws_size;

    float* w = (float*)d_ws;
    size_t off = 0;
    auto alloc = [&](size_t n) { float* p = w + off; off += n; return p; };
    unsigned short* pk2 = (unsigned short*)alloc(147456);
    unsigned short* pk3 = (unsigned short*)alloc(294912);
    unsigned short* pk4 = (unsigned short*)alloc(589824);
    unsigned short* pk5 = (unsigned short*)alloc(1179648);
    unsigned short* pk6 = (unsigned short*)alloc(2359296);
    float* wa1 = alloc(3456); float* wb1 = alloc(3456);
    float* ss2 = alloc(1152); float* ss3 = alloc(2304);
    float* ss5 = alloc(4608); float* ss6 = alloc(4608);
    float* og2 = alloc(32768); float* og3 = alloc(65536);
    float* og5 = alloc(32768); float* og6 = alloc(8192);
    float* st3 = alloc(512);  float* st6 = alloc(1024);
    float* A  = alloc(16777216);  // ex1 (bf16) / h3 (f32) -> pkF + pbuf
    float* Bb = alloc(4194304);   // ex2 (bf16) -> fco (f32) + h6b (bf16)
    float* Cc = alloc(8388608);   // h3t (bf16) -> h6 (f32)
    float* Dd = alloc(2097152);   // ex4 (bf16)
    float* Ee = alloc(4194304);   // ex5 (bf16)

    unsigned short* ex1 = (unsigned short*)A;
    float*          h3  = A;
    unsigned short* pkF = (unsigned short*)A;          // FC1 packed weights (16.8 MB), after bn_apply_t
    float*          pbuf = A + 4194304;                // FC1 split-K partials (8.4 MB)
    unsigned short* ex2 = (unsigned short*)Bb;
    float*          fco = Bb;                          // [0, 262144)
    unsigned short* h6b = (unsigned short*)(Bb + 524288); // h6 bf16 copy (4.2 MB)
    unsigned short* h3t = (unsigned short*)Cc;
    float*          h6  = Cc;
    unsigned short* ex4 = (unsigned short*)Dd;
    unsigned short* ex5 = (unsigned short*)Ee;

    // ---- prep ----
    prep_w<<<14, 256, 0, stream>>>(a1, b1, wa1, wb1, 3456);
    prep_pack<<<72,  256, 0, stream>>>(a2, b2, pk2, 128, 128, 1, 18432);
    prep_pack<<<144, 256, 0, stream>>>(a3, b3, pk3, 128, 256, 1, 36864);
    prep_pack<<<288, 256, 0, stream>>>(a4, b4, pk4, 256, 256, 0, 73728);
    prep_pack<<<576, 256, 0, stream>>>(a5, b5, pk5, 256, 512, 1, 147456);
    prep_pack<<<1152,256, 0, stream>>>(a6, b6, pk6, 512, 512, 1, 294912);
    prep_s<<<128, 64, 0, stream>>>(a2, ss2, 128);
    prep_s<<<256, 64, 0, stream>>>(a3, ss3, 128);
    prep_s<<<512, 64, 0, stream>>>(a5, ss5, 256);
    prep_s<<<512, 64, 0, stream>>>(a6, ss6, 512);
    prep_ones<<<128, 256, 0, stream>>>(ss2, og2, 128, 16, 16, 32, 32, 2, 32768);
    prep_ones<<<256, 256, 0, stream>>>(ss3, og3, 256, 16, 16, 16, 16, 1, 65536);
    prep_ones<<<128, 256, 0, stream>>>(ss5, og5, 512, 8, 8, 8, 8, 1, 32768);
    prep_ones<<<32,  256, 0, stream>>>(ss6, og6, 512, 4, 4, 8, 8, 2, 8192);

    // ---- network ----
    conv1_k<<<4096, 256, 0, stream>>>(x, wa1, wb1, c1, ex1);
    // L2: [256,32,32,128] -> [256,16,16,128]
    conv_mfma<128,32,32,128,16,16,2, 8,1,128,1><<<512, 256, 0, stream>>>(ex1, pk2, c2, og2, nullptr, ex2);
    // L3: -> h3 [256,256,16,16] NCHW f32 (sampled)
    conv_mfma<128,16,16,256,16,16,1, 8,1,128,2><<<1024, 256, 0, stream>>>(ex2, pk3, c3, og3, eps3, h3);
    // BN3 + relu + transpose to NHWC bf16
    hipMemsetAsync(st3, 0, 512 * sizeof(float), stream);
    bn_stats<<<dim3(256, 8), 256, 0, stream>>>(h3, st3, 256, 256, 32);
    bn_apply_t<<<4096, 256, 0, stream>>>(h3, st3, g3, be3, h3t);
    // FC1 weight pack into now-dead A region
    prep_fc1<<<4096, 256, 0, stream>>>(fc1w, pkF);
    // L4: [256,16,16,256] -> [256,8,8,256]
    conv_mfma<256,16,16,256, 8, 8,2, 8,2,128,0><<<256, 256, 0, stream>>>(h3t, pk4, c4, nullptr, nullptr, ex4);
    // L5: -> [256,8,8,512]
    conv_mfma<256, 8, 8,512, 8, 8,1, 8,2,128,1><<<512, 256, 0, stream>>>(ex4, pk5, c5, og5, nullptr, ex5);
    // L6: -> h6 [256,512,4,4] NCHW f32 (sampled)
    conv_mfma<512, 8, 8,512, 4, 4,2, 4,4, 64,2><<<256, 256, 0, stream>>>(ex5, pk6, c6, og6, eps6, h6);
    // BN6 + relu (in place) + bf16 copy for FC1
    hipMemsetAsync(st6, 0, 1024 * sizeof(float), stream);
    bn_stats<<<dim3(512, 8), 256, 0, stream>>>(h6, st6, 512, 16, 32);
    bn_apply<<<2048, 256, 0, stream>>>(h6, st6, g6, be6, h6b, 512, 16, (long)256 * 512 * 16, 1.f / 4096.f);
    // FC1: bf16 MFMA split-K + reduce(bias+relu)
    fc1_mfma<<<dim3(8, 4, 8), 256, 0, stream>>>(h6b, pkF, pbuf);
    fc1_reduce<<<1024, 256, 0, stream>>>(pbuf, fc1b, fco);
    // FC2
    fc2_k<<<256, 256, 0, stream>>>(fco, fc2w, fc2b, (float*)d_out);
}

// Round 5
// 955.464 us; speedup vs baseline: 5.9387x; 1.0447x over previous
//
#include <hip/hip_runtime.h>
#include <hip/hip_bf16.h>
#include <math.h>

#define EPSV 1e-10f
#define BNEPS 1e-5f
#define INV_SQRT2 0.70710678118654752440f

typedef __attribute__((ext_vector_type(8))) short short8;
typedef __attribute__((ext_vector_type(4))) float f32x4;

__device__ __forceinline__ float bf2f(unsigned short u) {
    union { unsigned int i; float f; } c; c.i = ((unsigned int)u) << 16; return c.f;
}
__device__ __forceinline__ unsigned short f2bf(float f) {
    unsigned int u = __float_as_uint(f);
    return (unsigned short)((u + 0x7FFFu + ((u >> 16) & 1u)) >> 16);
}
// elementwise bf16 square of a short8 fragment (same RNE rounding as f2bf)
__device__ __forceinline__ short8 sq8(short8 v) {
    short8 r;
    unsigned int* vp = (unsigned int*)&v;
    unsigned int* rp = (unsigned int*)&r;
#pragma unroll
    for (int e = 0; e < 4; e++) {
        unsigned int u = vp[e];
        float lo = __uint_as_float(u << 16);
        float hi = __uint_as_float(u & 0xffff0000u);
        rp[e] = (unsigned int)f2bf(lo * lo) | (((unsigned int)f2bf(hi * hi)) << 16);
    }
    return r;
}

// ---------------------------------------------------------------------------
// L1 weight prep (fp32, OIHW kept): e_w and var_w
// ---------------------------------------------------------------------------
__global__ void prep_w(const float* __restrict__ a, const float* __restrict__ b,
                       float* __restrict__ WA, float* __restrict__ WB, int n) {
    for (int i = blockIdx.x * blockDim.x + threadIdx.x; i < n; i += gridDim.x * blockDim.x) {
        float p0 = 1.f / (1.f + expf(-a[i]));
        float sb = 1.f / (1.f + expf(-b[i]));
        float p1 = (1.f - p0) * sb;
        float ew = 2.f * p1 - (1.f - p0);
        float ew2 = 1.f - p0;
        WA[i] = ew;
        WB[i] = ew2 - ew * ew;
    }
}

// ---------------------------------------------------------------------------
// Pack ternary-stat weights into MFMA A-fragment order (bf16).
// ---------------------------------------------------------------------------
__global__ void prep_pack(const float* __restrict__ a, const float* __restrict__ b,
                          unsigned short* __restrict__ pk, int Ci, int Co, int ver2, int total) {
    int idx = blockIdx.x * 256 + threadIdx.x;
    if (idx >= total) return;
    int lane = idx & 63;
    int MFg = Co >> 4, NCH = Ci >> 5;
    int mfch = idx >> 6;
    int mf = mfch % MFg;
    int chpos = mfch / MFg;
    int ch = chpos % NCH;
    int pos = chpos / NCH;
    int co = mf * 16 + (lane & 15);
    int cib = ch * 32 + (lane >> 4) * 8;
    unsigned int wa[4], wb[4];
#pragma unroll
    for (int j = 0; j < 8; j++) {
        long s = ((long)co * Ci + cib + j) * 9 + pos;
        float p0 = 1.f / (1.f + expf(-a[s]));
        float sb = 1.f / (1.f + expf(-b[s]));
        float p1 = (1.f - p0) * sb;
        float ew = 2.f * p1 - (1.f - p0);
        float ew2 = 1.f - p0;
        unsigned int ha = f2bf(ew);
        unsigned int hb = f2bf(ver2 ? ew * ew : ew2 - ew * ew);
        if (j & 1) { wa[j >> 1] |= ha << 16; wb[j >> 1] |= hb << 16; }
        else       { wa[j >> 1] = ha;        wb[j >> 1] = hb; }
    }
    long b0 = (((long)(0 * 9 + pos) * NCH + ch) * MFg + mf) * 64 + lane;
    long b1 = (((long)(1 * 9 + pos) * NCH + ch) * MFg + mf) * 64 + lane;
    uint4 va; va.x = wa[0]; va.y = wa[1]; va.z = wa[2]; va.w = wa[3];
    uint4 vb; vb.x = wb[0]; vb.y = wb[1]; vb.z = wb[2]; vb.w = wb[3];
    *(uint4*)(pk + b0 * 8) = va;
    *(uint4*)(pk + b1 * 8) = vb;
}

// ssum[co][k] = sum_ci sigmoid(-alpha)   (= sum_ci E[w^2])
__global__ void prep_s(const float* __restrict__ alpha, float* __restrict__ s, int Ci) {
    int co = blockIdx.x;
    int lane = threadIdx.x; // 64
    float acc[9];
#pragma unroll
    for (int k = 0; k < 9; k++) acc[k] = 0.f;
    for (int ci = lane; ci < Ci; ci += 64) {
        const float* p = alpha + ((long)co * Ci + ci) * 9;
#pragma unroll
        for (int k = 0; k < 9; k++) acc[k] += 1.f / (1.f + expf(p[k]));
    }
#pragma unroll
    for (int k = 0; k < 9; k++) {
        for (int off = 32; off > 0; off >>= 1) acc[k] += __shfl_down(acc[k], off);
    }
    if (lane == 0) {
#pragma unroll
        for (int k = 0; k < 9; k++) s[co * 9 + k] = acc[k];
    }
}

// ones_grid[co][y][x] = sum over valid (ky,kx) of ssum[co][ky*3+kx]
__global__ void prep_ones(const float* __restrict__ ssum, float* __restrict__ og,
                          int Co, int Hout, int Wout, int Hin, int Win, int stride, int total) {
    int idx = blockIdx.x * 256 + threadIdx.x;
    if (idx >= total) return;
    int x = idx % Wout, y = (idx / Wout) % Hout, co = idx / (Wout * Hout);
    float s = 0.f;
    for (int ky = 0; ky < 3; ky++) {
        int yi = stride * y - 1 + ky;
        if (yi < 0 || yi >= Hin) continue;
        for (int kx = 0; kx < 3; kx++) {
            int xi = stride * x - 1 + kx;
            if (xi < 0 || xi >= Win) continue;
            s += ssum[co * 9 + ky * 3 + kx];
        }
    }
    og[idx] = s;
}

// ---------------------------------------------------------------------------
// FC1 weight pack: fp32 [1024][8192] -> bf16 A-fragment order
// ---------------------------------------------------------------------------
__global__ void prep_fc1(const float* __restrict__ W, unsigned short* __restrict__ pk) {
    int idx = blockIdx.x * 256 + threadIdx.x;      // 1048576 total
    int lane = idx & 63;
    int mf = (idx >> 6) & 63;
    int kt = idx >> 12;
    int o = mf * 16 + (lane & 15);
    long k = (long)kt * 32 + (lane >> 4) * 8;
    const float* src = W + (long)o * 8192 + k;
    float4 f0 = *(const float4*)src;
    float4 f1 = *(const float4*)(src + 4);
    uint4 v;
    v.x = (unsigned)f2bf(f0.x) | ((unsigned)f2bf(f0.y) << 16);
    v.y = (unsigned)f2bf(f0.z) | ((unsigned)f2bf(f0.w) << 16);
    v.z = (unsigned)f2bf(f1.x) | ((unsigned)f2bf(f1.y) << 16);
    v.w = (unsigned)f2bf(f1.z) | ((unsigned)f2bf(f1.w) << 16);
    *(uint4*)(pk + (long)idx * 8) = v;
}

// ---------------------------------------------------------------------------
// L1: fp32 vector conv (Ci=3) -> erf -> NHWC bf16.
// ---------------------------------------------------------------------------
__global__ __launch_bounds__(256) void conv1_k(const float* __restrict__ x,
        const float* __restrict__ wa, const float* __restrict__ wb,
        const float* __restrict__ bias, unsigned short* __restrict__ out) {
    __shared__ float win[3 * 4 * 34];          // [ci][4 rows][34]
    __shared__ float wl[128 * 56];             // [co][28][(wa,wb)] interleaved
    int b = blockIdx.x >> 4;
    int y0 = (blockIdx.x & 15) * 2;
    int tid = threadIdx.x;
    for (int i = tid; i < 408; i += 256) {
        int ci = i / 136, r = (i % 136) / 34, px = i % 34;
        int yy = y0 - 1 + r, xx = px - 1;
        float v = 0.f;
        if (yy >= 0 && yy < 32 && xx >= 0 && xx < 32)
            v = x[((b * 3 + ci) * 32 + yy) * 32 + xx];
        win[i] = v;
    }
    for (int i = tid; i < 128 * 56; i += 256) {
        int co = i / 56, q = i % 56, j = q >> 1;
        float v = 0.f;
        if (j < 27) v = (q & 1) ? wb[co * 27 + j] : wa[co * 27 + j];
        wl[i] = v;
    }
    __syncthreads();
    int xo = tid & 31;
    int cog = tid >> 5;
    float iv[2][28], sq[2][28];
#pragma unroll
    for (int r = 0; r < 2; r++) {
#pragma unroll
        for (int ci = 0; ci < 3; ci++)
#pragma unroll
        for (int ky = 0; ky < 3; ky++)
#pragma unroll
        for (int kx = 0; kx < 3; kx++) {
            float v = win[(ci * 4 + r + ky) * 34 + xo + kx];
            iv[r][ci * 9 + ky * 3 + kx] = v;
            sq[r][ci * 9 + ky * 3 + kx] = v * v;
        }
        iv[r][27] = 0.f; sq[r][27] = 0.f;
    }
    unsigned int pk[2][8];
#pragma unroll
    for (int k = 0; k < 16; k++) {
        int co = cog * 16 + k;
        const float4* wp = (const float4*)&wl[co * 56];
        float bs = bias[co];
        float m0 = bs, v0 = 0.f, m1 = bs, v1 = 0.f;
#pragma unroll
        for (int q = 0; q < 14; q++) {
            float4 w4 = wp[q];
            m0 = fmaf(iv[0][2 * q], w4.x, m0);     v0 = fmaf(sq[0][2 * q], w4.y, v0);
            m0 = fmaf(iv[0][2 * q + 1], w4.z, m0); v0 = fmaf(sq[0][2 * q + 1], w4.w, v0);
            m1 = fmaf(iv[1][2 * q], w4.x, m1);     v1 = fmaf(sq[1][2 * q], w4.y, v1);
            m1 = fmaf(iv[1][2 * q + 1], w4.z, m1); v1 = fmaf(sq[1][2 * q + 1], w4.w, v1);
        }
        unsigned int h0 = f2bf(erff(m0 * rsqrtf(v0 + EPSV) * INV_SQRT2));
        unsigned int h1 = f2bf(erff(m1 * rsqrtf(v1 + EPSV) * INV_SQRT2));
        if (k & 1) { pk[0][k >> 1] |= h0 << 16; pk[1][k >> 1] |= h1 << 16; }
        else       { pk[0][k >> 1] = h0;        pk[1][k >> 1] = h1; }
    }
#pragma unroll
    for (int r = 0; r < 2; r++) {
        long oa = (((long)b * 32 + y0 + r) * 32 + xo) * 128 + cog * 16;
        uint4 u0; u0.x = pk[r][0]; u0.y = pk[r][1]; u0.z = pk[r][2]; u0.w = pk[r][3];
        uint4 u1; u1.x = pk[r][4]; u1.y = pk[r][5]; u1.z = pk[r][6]; u1.w = pk[r][7];
        *(uint4*)(out + oa) = u0;
        *(uint4*)(out + oa + 8) = u1;
    }
}

// ---------------------------------------------------------------------------
// MFMA implicit-GEMM fused LRnet conv. NHWC bf16 input. 512 threads, 8 waves.
// Squares computed in registers (no x^2 LDS array). XCD-aware ct swizzle.
// MODE 0: lrconv  -> erf -> NHWC bf16      (v = convB)
// MODE 1: ver2    -> erf -> NHWC bf16      (v = ones - convB)
// MODE 2: ver2 + sample -> NCHW fp32       (out = m + sqrt(v+eps)*epsb)
// ---------------------------------------------------------------------------
template<int Ci, int Hin, int Win, int Co, int Hout, int Wout, int STRIDE,
         int ROWS, int IPB, int NTILE, int MODE>
__global__ __launch_bounds__(512) void conv_mfma(
    const unsigned short* __restrict__ in,
    const unsigned short* __restrict__ wpk,
    const float* __restrict__ bias,
    const float* __restrict__ ones_g,
    const float* __restrict__ epsb,
    void* __restrict__ outp)
{
    constexpr int BLK = 512;
    constexpr int MTILE = 128;
    constexpr int PROWS = STRIDE * (ROWS - 1) + 3;
    constexpr int PW = Win + 2;
    constexpr int POS = IPB * PROWS * PW;
    constexpr int NCH = Ci / 32;
    constexpr int MFg = Co / 16;
    constexpr int NF = NTILE / 16;
    constexpr int WMF = 4;
    constexpr int WNF = NF / 4;
    constexpr int CT = Co / MTILE;
    constexpr int RG = Hout / ROWS;
    constexpr int LINE = 80;               // bytes per position (64 data + 16 pad)
    constexpr int TSTR = MTILE + 8;
    constexpr int STAGE_B = POS * LINE;
    constexpr int TR_B = (MODE == 2) ? 0 : NTILE * TSTR * 2;
    constexpr int LDS_B = STAGE_B > TR_B ? STAGE_B : TR_B;
    static_assert(8 % CT == 0, "ct swizzle");
    static_assert(WNF * 4 == NF, "wnf");
    __shared__ char lds[LDS_B];

    const int tid = threadIdx.x;
    const int lane = tid & 63;
    const int wv = tid >> 6;
    const int wm = wv & 1, wn = wv >> 1;   // wm: 0..1, wn: 0..3
    const int g = lane >> 4, ln = lane & 15;

    // XCD-aware swizzle: blocks on the same XCD (bid%8) share the same ct
    const int bid = blockIdx.x;
    const int xcd = bid & 7;
    constexpr int XPC = 8 / CT;
    const int ct = xcd % CT;
    const int nt = (bid >> 3) * XPC + xcd / CT;
    const int b0 = (nt / RG) * IPB;
    const int y0 = (nt % RG) * ROWS;

    int pbase[WNF];
#pragma unroll
    for (int nf = 0; nf < WNF; nf++) {
        int n = (wn * WNF + nf) * 16 + ln;
        int img = n / (ROWS * Wout);
        int rem = n % (ROWS * Wout);
        int yr = rem / Wout, xo = rem % Wout;
        pbase[nf] = (img * PROWS + STRIDE * yr) * PW + STRIDE * xo;
    }

    f32x4 accA[WMF][WNF], accB[WMF][WNF];
#pragma unroll
    for (int mf = 0; mf < WMF; mf++)
#pragma unroll
    for (int nf = 0; nf < WNF; nf++) {
        accA[mf][nf] = (f32x4){0.f, 0.f, 0.f, 0.f};
        accB[mf][nf] = (f32x4){0.f, 0.f, 0.f, 0.f};
    }

    const unsigned short* wbase = wpk + ((long)(ct * 8 + wm * WMF) * 64 + lane) * 8;

    for (int ch = 0; ch < NCH; ch++) {
        // ---- stage x (bf16) into LDS ----
        for (int i = tid; i < POS * 4; i += BLK) {
            int p = i >> 2, c = i & 3;
            int img = p / (PROWS * PW);
            int r = p % (PROWS * PW);
            int prow = r / PW, px = r % PW;
            int yin = STRIDE * y0 - 1 + prow;
            int xin = px - 1;
            uint4 v; v.x = 0; v.y = 0; v.z = 0; v.w = 0;
            if (yin >= 0 && yin < Hin && xin >= 0 && xin < Win) {
                long a = (((long)(b0 + img) * Hin + yin) * Win + xin) * Ci + ch * 32 + c * 8;
                v = *(const uint4*)(in + a);
            }
            *(uint4*)(lds + p * LINE + c * 16) = v;
        }
        __syncthreads();
        // ---- 9 kernel positions ----
#pragma unroll 3
        for (int pos = 0; pos < 9; pos++) {
            const int ky = pos / 3, kx = pos % 3;
            short8 af[2][WMF];
#pragma unroll
            for (int cv = 0; cv < 2; cv++)
#pragma unroll
            for (int mf = 0; mf < WMF; mf++)
                af[cv][mf] = *(const short8*)(wbase +
                    ((long)(((cv * 9 + pos) * NCH + ch) * MFg + mf)) * 512);
            short8 bx[WNF], bq[WNF];
#pragma unroll
            for (int nf = 0; nf < WNF; nf++) {
                int po = (pbase[nf] + ky * PW + kx) * LINE + g * 16;
                bx[nf] = *(const short8*)(lds + po);
                bq[nf] = sq8(bx[nf]);
            }
#pragma unroll
            for (int mf = 0; mf < WMF; mf++)
#pragma unroll
            for (int nf = 0; nf < WNF; nf++) {
                accA[mf][nf] = __builtin_amdgcn_mfma_f32_16x16x32_bf16(af[0][mf], bx[nf], accA[mf][nf], 0, 0, 0);
                accB[mf][nf] = __builtin_amdgcn_mfma_f32_16x16x32_bf16(af[1][mf], bq[nf], accB[mf][nf], 0, 0, 0);
            }
        }
        __syncthreads();
    }

    // ---- epilogue ----
    if constexpr (MODE == 2) {
        float* out = (float*)outp;
#pragma unroll
        for (int mf = 0; mf < WMF; mf++) {
            int co = ct * MTILE + (wm * WMF + mf) * 16 + g * 4;
#pragma unroll
            for (int nf = 0; nf < WNF; nf++) {
                int n = (wn * WNF + nf) * 16 + ln;
                int img = n / (ROWS * Wout), rem = n % (ROWS * Wout);
                int y = y0 + rem / Wout, x = rem % Wout;
                int b = b0 + img;
#pragma unroll
                for (int r = 0; r < 4; r++) {
                    int c = co + r;
                    float m = accA[mf][nf][r] + bias[c];
                    float v = ones_g[(c * Hout + y) * Wout + x] - accB[mf][nf][r];
                    long oi = (((long)b * Co + c) * Hout + y) * Wout + x;
                    out[oi] = m + sqrtf(v + EPSV) * epsb[oi];
                }
            }
        }
    } else {
        unsigned short* out = (unsigned short*)outp;
#pragma unroll
        for (int mf = 0; mf < WMF; mf++) {
            int cob = (wm * WMF + mf) * 16 + g * 4;
            int cg = ct * MTILE + cob;
#pragma unroll
            for (int nf = 0; nf < WNF; nf++) {
                int n = (wn * WNF + nf) * 16 + ln;
                int img = n / (ROWS * Wout), rem = n % (ROWS * Wout);
                int y = y0 + rem / Wout, x = rem % Wout;
                unsigned int pk2[2];
#pragma unroll
                for (int r = 0; r < 4; r++) {
                    int c = cg + r;
                    float m = accA[mf][nf][r] + bias[c];
                    float v;
                    if constexpr (MODE == 1)
                        v = ones_g[(c * Hout + y) * Wout + x] - accB[mf][nf][r];
                    else
                        v = accB[mf][nf][r];
                    unsigned int hv = f2bf(erff(m * rsqrtf(v + EPSV) * INV_SQRT2));
                    if (r & 1) pk2[r >> 1] |= hv << 16; else pk2[r >> 1] = hv;
                }
                *(unsigned int*)(lds + (n * TSTR + cob) * 2) = pk2[0];
                *(unsigned int*)(lds + (n * TSTR + cob) * 2 + 4) = pk2[1];
            }
        }
        __syncthreads();
        for (int i = tid; i < NTILE * (MTILE / 8); i += BLK) {
            int n = i / (MTILE / 8);
            int c8 = (i % (MTILE / 8)) * 8;
            int img = n / (ROWS * Wout), rem = n % (ROWS * Wout);
            int y = y0 + rem / Wout, x = rem % Wout;
            int b = b0 + img;
            uint4 val = *(const uint4*)(lds + (n * TSTR + c8) * 2);
            long oa = (((long)b * Hout + y) * Wout + x) * Co + ct * MTILE + c8;
            *(uint4*)(out + oa) = val;
        }
    }
}

// ---------------------------------------------------------------------------
// BatchNorm
// ---------------------------------------------------------------------------
__global__ void bn_stats(const float* __restrict__ h, float* __restrict__ st,
                         int C, int HW, int Bchunk) {
    int c = blockIdx.x;
    int chunk = blockIdx.y;
    int tid = threadIdx.x;
    float s = 0.f, s2 = 0.f;
    int total = Bchunk * HW;
    int bbase = chunk * Bchunk;
    for (int j = tid; j < total; j += 256) {
        int b = bbase + j / HW;
        int i = j % HW;
        float v = h[((long)b * C + c) * HW + i];
        s += v; s2 += v * v;
    }
    for (int off = 32; off > 0; off >>= 1) {
        s += __shfl_down(s, off);
        s2 += __shfl_down(s2, off);
    }
    __shared__ float red[8];
    int wid = tid >> 6, lane = tid & 63;
    if (lane == 0) { red[wid] = s; red[4 + wid] = s2; }
    __syncthreads();
    if (tid == 0) {
        atomicAdd(&st[c], red[0] + red[1] + red[2] + red[3]);
        atomicAdd(&st[C + c], red[4] + red[5] + red[6] + red[7]);
    }
}

// h6 in-place NCHW fp32 BN+relu, plus bf16 copy for FC1
__global__ void bn_apply(float* __restrict__ h, const float* __restrict__ st,
                         const float* __restrict__ gamma, const float* __restrict__ beta,
                         unsigned short* __restrict__ hb,
                         int C, int HW, long N, float invN) {
    for (long idx = (long)blockIdx.x * blockDim.x + threadIdx.x; idx < N;
         idx += (long)gridDim.x * blockDim.x) {
        int c = (int)((idx / HW) % C);
        float mean = st[c] * invN;
        float var = st[C + c] * invN - mean * mean;
        float v = gamma[c] * (h[idx] - mean) * rsqrtf(var + BNEPS) + beta[c];
        v = v > 0.f ? v : 0.f;
        h[idx] = v;
        hb[idx] = f2bf(v);
    }
}

// h3: NCHW fp32 -> BN+relu -> NHWC bf16 (block per (b,y), C=256, W=16)
__global__ __launch_bounds__(256) void bn_apply_t(const float* __restrict__ h,
        const float* __restrict__ st, const float* __restrict__ gamma,
        const float* __restrict__ beta, unsigned short* __restrict__ out) {
    __shared__ float t[256 * 17];
    int b = blockIdx.x >> 4, y = blockIdx.x & 15;
    int tid = threadIdx.x;
    const float invN = 1.f / 65536.f;
    for (int i = tid; i < 4096; i += 256) {
        int c = i >> 4, xx = i & 15;
        float mean = st[c] * invN;
        float var = st[256 + c] * invN - mean * mean;
        float v = h[(((long)b * 256 + c) * 16 + y) * 16 + xx];
        v = gamma[c] * (v - mean) * rsqrtf(var + BNEPS) + beta[c];
        t[c * 17 + xx] = v > 0.f ? v : 0.f;
    }
    __syncthreads();
    for (int i = tid; i < 4096; i += 256) {
        int xx = i >> 8, c = i & 255;
        out[(((long)b * 16 + y) * 16 + xx) * 256 + c] = f2bf(t[c * 17 + xx]);
    }
}

// ---------------------------------------------------------------------------
// FC1 bf16 MFMA split-K: pbuf[s][256][1024] partials
// ---------------------------------------------------------------------------
__global__ __launch_bounds__(256) void fc1_mfma(const unsigned short* __restrict__ Ab,
                                                const unsigned short* __restrict__ Wp,
                                                float* __restrict__ pbuf) {
    __shared__ char lds[2 * 64 * 80];
    const int tid = threadIdx.x;
    const int lane = tid & 63;
    const int wv = tid >> 6;
    const int g = lane >> 4, ln = lane & 15;
    const int ot = blockIdx.x, bt = blockIdx.y, s = blockIdx.z;
    const int b0 = bt * 64;
    const int k0g = s * 1024;

    f32x4 acc[2][4];
#pragma unroll
    for (int c = 0; c < 2; c++)
#pragma unroll
    for (int nf = 0; nf < 4; nf++) acc[c][nf] = (f32x4){0.f, 0.f, 0.f, 0.f};

    for (int k0 = 0; k0 < 1024; k0 += 64) {
        __syncthreads();
        for (int i = tid; i < 512; i += 256) {
            int row = i >> 3, kk = (i >> 2) & 1, seg = i & 3;
            uint4 v = *(const uint4*)(Ab + ((long)(b0 + row) * 8192 + k0g + k0 + kk * 32 + seg * 8));
            *(uint4*)(lds + (kk * 64 + row) * 80 + seg * 16) = v;
        }
        __syncthreads();
#pragma unroll
        for (int kk = 0; kk < 2; kk++) {
            int kt = (k0g + k0) / 32 + kk;
            short8 af[2];
#pragma unroll
            for (int c = 0; c < 2; c++) {
                int mf = ot * 8 + wv * 2 + c;
                af[c] = *(const short8*)(Wp + (((long)kt * 64 + mf) * 64 + lane) * 8);
            }
            short8 bf[4];
#pragma unroll
            for (int nf = 0; nf < 4; nf++)
                bf[nf] = *(const short8*)(lds + (kk * 64 + nf * 16 + ln) * 80 + g * 16);
#pragma unroll
            for (int c = 0; c < 2; c++)
#pragma unroll
            for (int nf = 0; nf < 4; nf++)
                acc[c][nf] = __builtin_amdgcn_mfma_f32_16x16x32_bf16(af[c], bf[nf], acc[c][nf], 0, 0, 0);
        }
    }
#pragma unroll
    for (int c = 0; c < 2; c++) {
        int o = ot * 128 + (wv * 2 + c) * 16 + g * 4;
#pragma unroll
        for (int nf = 0; nf < 4; nf++) {
            int b = b0 + nf * 16 + ln;
            *(f32x4*)(pbuf + ((long)s * 256 + b) * 1024 + o) = acc[c][nf];
        }
    }
}

__global__ void fc1_reduce(const float* __restrict__ pbuf, const float* __restrict__ bias,
                           float* __restrict__ out) {
    int idx = blockIdx.x * 256 + threadIdx.x;   // 262144
    float s = 0.f;
#pragma unroll
    for (int j = 0; j < 8; j++) s += pbuf[(long)j * 262144 + idx];
    s += bias[idx & 1023];
    out[idx] = s > 0.f ? s : 0.f;
}

__global__ void fc2_k(const float* __restrict__ A, const float* __restrict__ W,
                      const float* __restrict__ b2, float* __restrict__ out) {
    int bb = blockIdx.x;
    int tid = threadIdx.x;
    float acc[10];
#pragma unroll
    for (int o = 0; o < 10; o++) acc[o] = 0.f;
    const float* arow = A + (long)bb * 1024;
    for (int k = tid; k < 1024; k += 256) {
        float a = arow[k];
#pragma unroll
        for (int o = 0; o < 10; o++) acc[o] = fmaf(a, W[o * 1024 + k], acc[o]);
    }
#pragma unroll
    for (int o = 0; o < 10; o++)
        for (int off = 32; off > 0; off >>= 1) acc[o] += __shfl_down(acc[o], off);
    __shared__ float red[10][4];
    int wid = tid >> 6, lane = tid & 63;
    if (lane == 0) {
#pragma unroll
        for (int o = 0; o < 10; o++) red[o][wid] = acc[o];
    }
    __syncthreads();
    if (tid < 10)
        out[bb * 10 + tid] = red[tid][0] + red[tid][1] + red[tid][2] + red[tid][3] + b2[tid];
}

// ---------------------------------------------------------------------------
extern "C" void kernel_launch(void* const* d_in, const int* in_sizes, int n_in,
                              void* d_out, int out_size, void* d_ws, size_t ws_size,
                              hipStream_t stream) {
    const float* x  = (const float*)d_in[0];
    const float* a1 = (const float*)d_in[1];  const float* b1 = (const float*)d_in[2];  const float* c1 = (const float*)d_in[3];
    const float* a2 = (const float*)d_in[4];  const float* b2 = (const float*)d_in[5];  const float* c2 = (const float*)d_in[6];
    const float* a3 = (const float*)d_in[7];  const float* b3 = (const float*)d_in[8];  const float* c3 = (const float*)d_in[9];
    const float* a4 = (const float*)d_in[10]; const float* b4 = (const float*)d_in[11]; const float* c4 = (const float*)d_in[12];
    const float* a5 = (const float*)d_in[13]; const float* b5 = (const float*)d_in[14]; const float* c5 = (const float*)d_in[15];
    const float* a6 = (const float*)d_in[16]; const float* b6 = (const float*)d_in[17]; const float* c6 = (const float*)d_in[18];
    const float* g3 = (const float*)d_in[19]; const float* be3 = (const float*)d_in[20];
    const float* g6 = (const float*)d_in[21]; const float* be6 = (const float*)d_in[22];
    const float* fc1w = (const float*)d_in[23]; const float* fc1b = (const float*)d_in[24];
    const float* fc2w = (const float*)d_in[25]; const float* fc2b = (const float*)d_in[26];
    const float* eps3 = (const float*)d_in[27]; const float* eps6 = (const float*)d_in[28];
    (void)in_sizes; (void)n_in; (void)out_size; (void)ws_size;

    float* w = (float*)d_ws;
    size_t off = 0;
    auto alloc = [&](size_t n) { float* p = w + off; off += n; return p; };
    unsigned short* pk2 = (unsigned short*)alloc(147456);
    unsigned short* pk3 = (unsigned short*)alloc(294912);
    unsigned short* pk4 = (unsigned short*)alloc(589824);
    unsigned short* pk5 = (unsigned short*)alloc(1179648);
    unsigned short* pk6 = (unsigned short*)alloc(2359296);
    float* wa1 = alloc(3456); float* wb1 = alloc(3456);
    float* ss2 = alloc(1152); float* ss3 = alloc(2304);
    float* ss5 = alloc(4608); float* ss6 = alloc(4608);
    float* og2 = alloc(32768); float* og3 = alloc(65536);
    float* og5 = alloc(32768); float* og6 = alloc(8192);
    float* st3 = alloc(512);  float* st6 = alloc(1024);
    float* A  = alloc(16777216);  // ex1 (bf16) / h3 (f32) -> pkF + pbuf
    float* Bb = alloc(4194304);   // ex2 (bf16) -> fco (f32) + h6b (bf16)
    float* Cc = alloc(8388608);   // h3t (bf16) -> h6 (f32)
    float* Dd = alloc(2097152);   // ex4 (bf16)
    float* Ee = alloc(4194304);   // ex5 (bf16)

    unsigned short* ex1 = (unsigned short*)A;
    float*          h3  = A;
    unsigned short* pkF = (unsigned short*)A;          // FC1 packed weights (16.8 MB), after bn_apply_t
    float*          pbuf = A + 4194304;                // FC1 split-K partials (8.4 MB)
    unsigned short* ex2 = (unsigned short*)Bb;
    float*          fco = Bb;                          // [0, 262144)
    unsigned short* h6b = (unsigned short*)(Bb + 524288); // h6 bf16 copy (4.2 MB)
    unsigned short* h3t = (unsigned short*)Cc;
    float*          h6  = Cc;
    unsigned short* ex4 = (unsigned short*)Dd;
    unsigned short* ex5 = (unsigned short*)Ee;

    // ---- prep ----
    prep_w<<<14, 256, 0, stream>>>(a1, b1, wa1, wb1, 3456);
    prep_pack<<<72,  256, 0, stream>>>(a2, b2, pk2, 128, 128, 1, 18432);
    prep_pack<<<144, 256, 0, stream>>>(a3, b3, pk3, 128, 256, 1, 36864);
    prep_pack<<<288, 256, 0, stream>>>(a4, b4, pk4, 256, 256, 0, 73728);
    prep_pack<<<576, 256, 0, stream>>>(a5, b5, pk5, 256, 512, 1, 147456);
    prep_pack<<<1152,256, 0, stream>>>(a6, b6, pk6, 512, 512, 1, 294912);
    prep_s<<<128, 64, 0, stream>>>(a2, ss2, 128);
    prep_s<<<256, 64, 0, stream>>>(a3, ss3, 128);
    prep_s<<<512, 64, 0, stream>>>(a5, ss5, 256);
    prep_s<<<512, 64, 0, stream>>>(a6, ss6, 512);
    prep_ones<<<128, 256, 0, stream>>>(ss2, og2, 128, 16, 16, 32, 32, 2, 32768);
    prep_ones<<<256, 256, 0, stream>>>(ss3, og3, 256, 16, 16, 16, 16, 1, 65536);
    prep_ones<<<128, 256, 0, stream>>>(ss5, og5, 512, 8, 8, 8, 8, 1, 32768);
    prep_ones<<<32,  256, 0, stream>>>(ss6, og6, 512, 4, 4, 8, 8, 2, 8192);

    // ---- network ----
    conv1_k<<<4096, 256, 0, stream>>>(x, wa1, wb1, c1, ex1);
    // L2: [256,32,32,128] -> [256,16,16,128]
    conv_mfma<128,32,32,128,16,16,2, 8,1,128,1><<<512, 512, 0, stream>>>(ex1, pk2, c2, og2, nullptr, ex2);
    // L3: -> h3 [256,256,16,16] NCHW f32 (sampled)
    conv_mfma<128,16,16,256,16,16,1, 8,1,128,2><<<1024, 512, 0, stream>>>(ex2, pk3, c3, og3, eps3, h3);
    // BN3 + relu + transpose to NHWC bf16
    hipMemsetAsync(st3, 0, 512 * sizeof(float), stream);
    bn_stats<<<dim3(256, 8), 256, 0, stream>>>(h3, st3, 256, 256, 32);
    bn_apply_t<<<4096, 256, 0, stream>>>(h3, st3, g3, be3, h3t);
    // FC1 weight pack into now-dead A region
    prep_fc1<<<4096, 256, 0, stream>>>(fc1w, pkF);
    // L4: [256,16,16,256] -> [256,8,8,256]  (IPB=1 -> grid 512)
    conv_mfma<256,16,16,256, 8, 8,2, 8,1,64,0><<<512, 512, 0, stream>>>(h3t, pk4, c4, nullptr, nullptr, ex4);
    // L5: -> [256,8,8,512]
    conv_mfma<256, 8, 8,512, 8, 8,1, 8,2,128,1><<<512, 512, 0, stream>>>(ex4, pk5, c5, og5, nullptr, ex5);
    // L6: -> h6 [256,512,4,4] NCHW f32 (sampled)
    conv_mfma<512, 8, 8,512, 4, 4,2, 4,4, 64,2><<<256, 512, 0, stream>>>(ex5, pk6, c6, og6, eps6, h6);
    // BN6 + relu (in place) + bf16 copy for FC1
    hipMemsetAsync(st6, 0, 1024 * sizeof(float), stream);
    bn_stats<<<dim3(512, 8), 256, 0, stream>>>(h6, st6, 512, 16, 32);
    bn_apply<<<2048, 256, 0, stream>>>(h6, st6, g6, be6, h6b, 512, 16, (long)256 * 512 * 16, 1.f / 4096.f);
    // FC1: bf16 MFMA split-K + reduce(bias+relu)
    fc1_mfma<<<dim3(8, 4, 8), 256, 0, stream>>>(h6b, pkF, pbuf);
    fc1_reduce<<<1024, 256, 0, stream>>>(pbuf, fc1b, fco);
    // FC2
    fc2_k<<<256, 256, 0, stream>>>(fco, fc2w, fc2b, (float*)d_out);
}